// Round 9
// baseline (481.523 us; speedup 1.0000x reference)
//
#include <hip/hip_runtime.h>
#include <math.h>

typedef long long i64;
typedef __attribute__((ext_vector_type(8))) short bf16x8;
typedef __attribute__((ext_vector_type(4))) float f32x4;

#define TEMP_ISQ 0.047245559f   // 1/sqrt(448)

__device__ __forceinline__ unsigned short f2b(float x) {
  union { float f; unsigned u; } a; a.f = x;
  return (unsigned short)((a.u + 0x7fffu + ((a.u >> 16) & 1u)) >> 16);
}
__device__ __forceinline__ float b2f(unsigned short b) {
  union { float f; unsigned u; } a; a.u = ((unsigned)b) << 16; return a.f;
}

// ================= NT bf16 MFMA GEMM =================
// out[M,N] = A[M,K] @ BT[N,K]^T (+bias). 128x128 tile, BK=32 double-buffered,
// ONE barrier per K-step. T1 chunked XCD swizzle (nwg % 8 == 0). LDS slot XOR
// f(r)=(r>>1)&3 on BOTH staged source and ds_read (rule #21).
// BIAS: 0 none, 1 col bias, 2 row bias
// OUTM: 0 fp32, 1 bf16, 2 both, 3 fp32 tanh(acc/3),
//       4 fp32: col<28 tanh(acc/3), col 28..30 acc/1024 (OV+Rdiag fusion)
// RS:   1 -> v *= tanhf(rowScale[zA*sRS + row] + rsAdd[zA])
// BZDIV: B batch index = z / BZDIV (XMODE 0)
// XMODE: 0 normal
//        2 PL (zA=z/3: A per zA, B per z, col-bias per z)
//        3 W2T (z->(b,i): A=KVR+b*sA+doff_i, B=wqB+doff_i, Kd=d_i)
//        5 logits-pack: z<32 -> {A=Ab+z*sA, B=Bb, bias}, z>=32 -> {A=Ab+z*sA,
//          B=Bb2, bias2, row-offset 256}; output batch z&31
//        6 CT-pack: z<32 -> {A=Ab, B=Bb+z*sB, rowbias}, z>=32 -> {A=Ab2,
//          B=Bb+z*sB, rowbias2, col-offset 256}; output batch z&31
// SMEPI: 2 -> row softmax epilogue, bf16 TRANSPOSED store (Nn==128, gridx==1)
template<int BIAS, int OUTM, int RS, int BZDIV, int XMODE = 0, int SMEPI = 0>
__global__ __launch_bounds__(256)
void gemm_mfma(const unsigned short* __restrict__ Ab, i64 sA,
               const unsigned short* __restrict__ Bb, i64 sB,
               const unsigned short* __restrict__ Ab2,
               const unsigned short* __restrict__ Bb2,
               const float* __restrict__ bias, const float* __restrict__ bias2,
               void* __restrict__ Ob, i64 sO,
               unsigned short* __restrict__ O2b, i64 sO2,
               int Nn, int Kd, int ldA, int ldB, int ldO,
               const float* __restrict__ rowScale, i64 sRS,
               const float* __restrict__ rsAdd)
{
  __shared__ unsigned short As[2][4096];
  __shared__ unsigned short Bs[2][4096];
  const int tid = threadIdx.x;
  const int w = tid >> 6, lane = tid & 63;

  // T1 chunked XCD swizzle
  const int gx = gridDim.x, gy = gridDim.y;
  int nwg = gx * gy * gridDim.z;
  int bid = blockIdx.x + gx * (blockIdx.y + gy * blockIdx.z);
  int L = bid;
  if ((nwg & 7) == 0) L = (bid & 7) * (nwg >> 3) + (bid >> 3);
  const int bx = L % gx;
  int rem = L / gx;
  const int by = rem % gy;
  const int z  = rem / gy;

  const int m0 = by * 128, n0 = bx * 128;
  int zA = (XMODE == 2) ? z / 3 : z;
  int zOut = z, colOff = 0, mOff = 0;
  const unsigned short* A;
  const unsigned short* B;
  int KdL = Kd;
  if (XMODE == 3) {
    int bb = z / 3, ii = z - bb * 3;
    const int dof_[3] = {0, 256, 384};
    const int kdt_[3] = {256, 128, 64};
    A = Ab + (i64)bb * sA + dof_[ii];
    B = Bb + dof_[ii];
    KdL = kdt_[ii];
  } else if (XMODE == 2) {
    A = Ab + (i64)zA * sA;
    B = Bb + (i64)z * sB;
  } else if (XMODE == 5) {
    A = Ab + (i64)z * sA;
    B = (z >= 32) ? Bb2 : Bb;
    zOut = z & 31;
    mOff = (z >= 32) ? 256 : 0;
  } else if (XMODE == 6) {
    A = (z >= 32) ? Ab2 : Ab;
    B = Bb + (i64)z * sB;
    zOut = z & 31;
    colOff = (z >= 32) ? 256 : 0;
  } else {
    A = Ab + (i64)z * sA;
    B = Bb + (i64)(BZDIV == 1 ? z : z / BZDIV) * sB;
  }
  const float* bcol = (XMODE == 2) ? (bias + (i64)z * 128)
                    : ((XMODE == 5 && z >= 32) ? bias2 : bias);
  const float* brow = (XMODE == 6 && z >= 32) ? bias2 : bias;

  const int wr = w >> 1, wc = w & 1;
  const int rS = tid >> 2, sS = tid & 3;
  const int cL = lane & 15, sl = lane >> 4;

  f32x4 acc[4][4];
  #pragma unroll
  for (int i = 0; i < 4; ++i)
    #pragma unroll
    for (int j = 0; j < 4; ++j) acc[i][j] = (f32x4){0.f, 0.f, 0.f, 0.f};

  auto STAGE = [&](int buf, int k0) {
    #pragma unroll
    for (int q = 0; q < 2; ++q) {
      int r = rS + q * 64;
      int sg = sS ^ ((r >> 1) & 3);
      const unsigned short* sa = A + (i64)(m0 + r) * ldA + k0 + sg * 8;
      const unsigned short* sb = B + (i64)(n0 + r) * ldB + k0 + sg * 8;
      __builtin_amdgcn_global_load_lds(
          (__attribute__((address_space(1))) void*)sa,
          (__attribute__((address_space(3))) void*)&As[buf][r * 32 + sS * 8], 16, 0, 0);
      __builtin_amdgcn_global_load_lds(
          (__attribute__((address_space(1))) void*)sb,
          (__attribute__((address_space(3))) void*)&Bs[buf][r * 32 + sS * 8], 16, 0, 0);
    }
  };

  STAGE(0, 0);
  __syncthreads();

  for (int k0 = 0; k0 < KdL; k0 += 32) {
    const int cur = (k0 >> 5) & 1;
    if (k0 + 32 < KdL) STAGE(cur ^ 1, k0 + 32);
    bf16x8 af[4], bfv[4];
    #pragma unroll
    for (int mi = 0; mi < 4; ++mi) {
      int rr = wr * 64 + mi * 16 + cL;
      int ph = sl ^ ((rr >> 1) & 3);
      af[mi] = *(const bf16x8*)&As[cur][rr * 32 + ph * 8];
    }
    #pragma unroll
    for (int ni = 0; ni < 4; ++ni) {
      int rr = wc * 64 + ni * 16 + cL;
      int ph = sl ^ ((rr >> 1) & 3);
      bfv[ni] = *(const bf16x8*)&Bs[cur][rr * 32 + ph * 8];
    }
    #pragma unroll
    for (int mi = 0; mi < 4; ++mi)
      #pragma unroll
      for (int ni = 0; ni < 4; ++ni)
        acc[mi][ni] = __builtin_amdgcn_mfma_f32_16x16x32_bf16(af[mi], bfv[ni], acc[mi][ni], 0, 0, 0);
    __syncthreads();
  }

  // D layout: col=lane&15, row=(lane>>4)*4+reg
  if constexpr (SMEPI == 2) {
    #pragma unroll
    for (int mi = 0; mi < 4; ++mi)
      #pragma unroll
      for (int ni = 0; ni < 4; ++ni)
        #pragma unroll
        for (int rg = 0; rg < 4; ++rg) {
          float v = acc[mi][ni][rg];
          if (BIAS == 1) v += bcol[wc * 64 + ni * 16 + cL];
          acc[mi][ni][rg] = v;
        }
    __shared__ float smax[2][128];
    __shared__ float ssum[2][128];
    #pragma unroll
    for (int mi = 0; mi < 4; ++mi)
      #pragma unroll
      for (int rg = 0; rg < 4; ++rg) {
        float m = fmaxf(fmaxf(acc[mi][0][rg], acc[mi][1][rg]),
                        fmaxf(acc[mi][2][rg], acc[mi][3][rg]));
        #pragma unroll
        for (int o = 1; o < 16; o <<= 1) m = fmaxf(m, __shfl_xor(m, o));
        if (cL == 0) smax[wc][wr * 64 + mi * 16 + sl * 4 + rg] = m;
      }
    __syncthreads();
    #pragma unroll
    for (int mi = 0; mi < 4; ++mi)
      #pragma unroll
      for (int rg = 0; rg < 4; ++rg) {
        int r = wr * 64 + mi * 16 + sl * 4 + rg;
        float m = fmaxf(smax[0][r], smax[1][r]);
        float s = 0.f;
        #pragma unroll
        for (int ni = 0; ni < 4; ++ni) s += expf(acc[mi][ni][rg] - m);
        #pragma unroll
        for (int o = 1; o < 16; o <<= 1) s += __shfl_xor(s, o);
        if (cL == 0) ssum[wc][r] = s;
      }
    __syncthreads();
    unsigned short* OP = (unsigned short*)Ob + (i64)zOut * sO;
    #pragma unroll
    for (int mi = 0; mi < 4; ++mi)
      #pragma unroll
      for (int rg = 0; rg < 4; ++rg) {
        int r = wr * 64 + mi * 16 + sl * 4 + rg;
        float m = fmaxf(smax[0][r], smax[1][r]);
        float inv = 1.f / (ssum[0][r] + ssum[1][r]);
        #pragma unroll
        for (int ni = 0; ni < 4; ++ni) {
          int c = wc * 64 + ni * 16 + cL;
          OP[(i64)c * ldO + mOff + m0 + r] = f2b(expf(acc[mi][ni][rg] - m) * inv);
        }
      }
    return;
  } else {
    #pragma unroll
    for (int mi = 0; mi < 4; ++mi) {
      const int rowb = m0 + wr * 64 + mi * 16 + sl * 4;
      #pragma unroll
      for (int ni = 0; ni < 4; ++ni) {
        const int col = n0 + wc * 64 + ni * 16 + cL;
        if (col < Nn) {
          float bc = (BIAS == 1) ? bcol[col] : 0.f;
          #pragma unroll
          for (int rg = 0; rg < 4; ++rg) {
            float v = acc[mi][ni][rg];
            if (RS) v *= tanhf(rowScale[(i64)zA * sRS + rowb + rg] + rsAdd[zA]);
            v += bc;
            if (BIAS == 2) v += brow[rowb + rg];
            i64 oidx = (i64)(rowb + rg) * ldO + colOff + col;
            if (OUTM == 0)      ((float*)Ob)[(i64)zOut * sO + oidx] = v;
            else if (OUTM == 1) ((unsigned short*)Ob)[(i64)zOut * sO + oidx] = f2b(v);
            else if (OUTM == 3) ((float*)Ob)[(i64)zOut * sO + oidx] = tanhf(v * (1.f / 3.f));
            else if (OUTM == 4) {
              float ov = (col < 28) ? tanhf(v * (1.f / 3.f)) : v * (1.f / 1024.f);
              ((float*)Ob)[(i64)zOut * sO + oidx] = ov;
            } else {
              ((float*)Ob)[(i64)zOut * sO + oidx] = v;
              O2b[(i64)zOut * sO2 + oidx] = f2b(v);
            }
          }
        }
      }
    }
  }
}

// ================= fused emo pass =================
__global__ __launch_bounds__(256)
void emo_pass1(const float* __restrict__ emo, const float* __restrict__ eleW,
               unsigned short* __restrict__ emoB, float* __restrict__ colPart,
               float* __restrict__ dotE) {
  int b = blockIdx.y, lc = blockIdx.x;   // 64 chunks x 16 rows
  int t = threadIdx.x, lane = t & 63, w = t >> 6;
  float4 w4 = ((const float4*)eleW)[t];
  float4 acc = make_float4(0.f, 0.f, 0.f, 0.f);
  __shared__ float dw[16][4];
  const float4* src = (const float4*)emo + ((i64)b * 1024 + lc * 16) * 256;
  ushort4* dst = (ushort4*)emoB + ((i64)b * 1024 + lc * 16) * 256;
  #pragma unroll 4
  for (int lr = 0; lr < 16; ++lr) {
    float4 v = src[lr * 256 + t];
    acc.x += v.x; acc.y += v.y; acc.z += v.z; acc.w += v.w;
    float d = v.x * w4.x + v.y * w4.y + v.z * w4.z + v.w * w4.w;
    #pragma unroll
    for (int o = 32; o; o >>= 1) d += __shfl_xor(d, o);
    if (!lane) dw[lr][w] = d;
    ushort4 o4; o4.x = f2b(v.x); o4.y = f2b(v.y); o4.z = f2b(v.z); o4.w = f2b(v.w);
    dst[lr * 256 + t] = o4;
  }
  __syncthreads();
  if (t < 16) dotE[(i64)b * 1024 + lc * 16 + t] = dw[t][0] + dw[t][1] + dw[t][2] + dw[t][3];
  ((float4*)colPart)[((i64)b * 64 + lc) * 256 + t] = acc;
}

// ================= prep kernels =================
// transposes: aaT(4), acT(32), wk(14), wv(1), wr(1); converts: wqB(14), wvB(32).
// grid (98, 32).
__global__ __launch_bounds__(256)
void transpose_all(const float* __restrict__ agg_a_W, const float* __restrict__ agg_c_W,
                   const float* __restrict__ wq_W, const float* __restrict__ w_v_W,
                   const float* __restrict__ wk_W, const float* __restrict__ wv_W,
                   const float* __restrict__ wr_W,
                   unsigned short* __restrict__ aaT, unsigned short* __restrict__ acT,
                   unsigned short* __restrict__ wqB, unsigned short* __restrict__ wvB,
                   unsigned short* __restrict__ kvrT) {
  int bx = blockIdx.x;
  int t = threadIdx.x;
  if (bx >= 52) {
    const float* in; unsigned short* out; int base;
    if (bx < 66) { in = wq_W;  out = wqB; base = bx - 52; }   // [1024x448] 448 slices
    else         { in = w_v_W; out = wvB; base = bx - 66; }   // [1024x1024] 1024 slices
    i64 li = (((i64)base * 32 + blockIdx.y) * 256 + t) * 4;
    float4 v = *(const float4*)(in + li);
    ushort4 o; o.x = f2b(v.x); o.y = f2b(v.y); o.z = f2b(v.z); o.w = f2b(v.w);
    *(ushort4*)(out + li) = o;
    return;
  }
  __shared__ float T[32][33];
  const float* in; unsigned short* out; int N, Npad, s0;
  if (bx < 4)       { in = agg_a_W; out = aaT;                     N = 128;  Npad = 128;  s0 = 0; }
  else if (bx < 36) { in = agg_c_W; out = acT;                     N = 1024; Npad = 1024; s0 = 4; }
  else if (bx < 50) { in = wk_W;    out = kvrT;                    N = 448;  Npad = 448;  s0 = 36; }
  else if (bx < 51) { in = wv_W;    out = kvrT + (i64)448 * 1024;  N = 28;   Npad = 28;   s0 = 50; }
  else              { in = wr_W;    out = kvrT + (i64)476 * 1024;  N = 3;    Npad = 36;   s0 = 51; }
  int n0 = (bx - s0) * 32, k0 = blockIdx.y * 32;
  #pragma unroll
  for (int p = 0; p < 4; ++p) {
    int idx = t + 256 * p; int kk = idx >> 5, nn = idx & 31;
    float v = 0.f;
    if (n0 + nn < N) v = in[(i64)(k0 + kk) * N + (n0 + nn)];
    T[nn][kk] = v;
  }
  __syncthreads();
  #pragma unroll
  for (int p = 0; p < 4; ++p) {
    int idx = t + 256 * p; int nn = idx >> 5, kk = idx & 31;
    if (n0 + nn < Npad) out[(i64)(n0 + nn) * 1024 + (k0 + kk)] = f2b(T[nn][kk]);
  }
}

// kvrB (480) + cbrow[e]=agg_c_b+wvb@agg_c (1024) + ab2[k]=agg_a_b+wvb@agg_a (128)
__global__ void bias_prep(const float* wkb, const float* wvb, const float* wrb,
                          const float* __restrict__ agg_c_W, const float* agg_c_b,
                          const float* __restrict__ agg_a_W, const float* agg_a_b,
                          const float* __restrict__ w_v_b,
                          float* kvrB, float* cbrow, float* ab2) {
  int bx = blockIdx.x, t = threadIdx.x;
  if (bx < 2) {
    int i = bx * 256 + t;
    if (i < 480)
      kvrB[i] = (i < 448) ? wkb[i] : (i < 476) ? wvb[i - 448] : (i < 479) ? wrb[i - 476] : 0.f;
  } else if (bx < 6) {
    int e = (bx - 2) * 256 + t;
    float s = agg_c_b[e];
    for (int f = 0; f < 1024; ++f) s += w_v_b[f] * agg_c_W[(i64)f * 1024 + e];
    cbrow[e] = s;
  } else if (t < 128) {
    float s = agg_a_b[t];
    for (int f = 0; f < 1024; ++f) s += w_v_b[f] * agg_a_W[(i64)f * 128 + t];
    ab2[t] = s;
  }
}

// fused pool_phr + video bf16 convert (grid 16384)
__global__ void pv_conv(const float* __restrict__ phr, const float* __restrict__ video,
                        unsigned short* __restrict__ pooled, unsigned short* __restrict__ videoB) {
  i64 idx = (i64)blockIdx.x * 256 + threadIdx.x;
  if (idx < 2097152) {
    i64 bm = idx >> 8; int c = (int)(idx & 255);
    i64 b = bm >> 8, m = bm & 255;
    const float4* r0 = (const float4*)(phr + (b * 512 + 2 * m) * 1024) + c;
    const float4* r1 = (const float4*)(phr + (b * 512 + 2 * m + 1) * 1024) + c;
    float4 a = *r0, d = *r1;
    ushort4 o;
    o.x = f2b(0.5f * (a.x + d.x)); o.y = f2b(0.5f * (a.y + d.y));
    o.z = f2b(0.5f * (a.z + d.z)); o.w = f2b(0.5f * (a.w + d.w));
    ((ushort4*)pooled)[idx] = o;
  } else {
    i64 j = idx - 2097152;
    float4 v = ((const float4*)video)[j];
    ushort4 o;
    o.x = f2b(v.x); o.y = f2b(v.y); o.z = f2b(v.z); o.w = f2b(v.w);
    ((ushort4*)videoB)[j] = o;
  }
}

// fused vt_fill (+R rows 28..30) and qb. grid (67, 32).
__global__ void vtq_fill(const unsigned short* __restrict__ KVR, const float* __restrict__ wq_b,
                         unsigned short* __restrict__ VT, float* __restrict__ qb) {
  int b = blockIdx.y, bx = blockIdx.x, t = threadIdx.x;
  if (bx < 64) {
    int idx = bx * 256 + t;
    int n = idx >> 7, k = idx & 127;
    unsigned short v = 0;
    if (n < 28)      v = KVR[(i64)b * 61440 + k * 480 + 448 + n];
    else if (n < 31) v = KVR[(i64)b * 61440 + k * 480 + 476 + (n - 28)];
    VT[((i64)b * 128 + n) * 128 + k] = v;
  } else if (t < 128) {
    int ii = bx - 64;
    const int dof_[3] = {0, 256, 384};
    const int kdt_[3] = {256, 128, 64};
    const unsigned short* kp = KVR + (i64)b * 61440 + t * 480 + dof_[ii];
    const float* wb = wq_b + dof_[ii];
    float s = 0.f;
    for (int d = 0; d < kdt_[ii]; ++d) s += b2f(kp[d]) * wb[d];
    qb[(b * 3 + ii) * 128 + t] = s;
  }
}

// ================= softmax =================
// in-place: each warp owns one row of PL
__global__ void softmax_P_bf(const unsigned short* __restrict__ PL, unsigned short* __restrict__ P) {
  i64 gw = ((i64)blockIdx.x * blockDim.x + threadIdx.x) >> 6;
  int lane = threadIdx.x & 63;
  if (gw >= 98304) return;
  const unsigned short* p = PL + gw * 128;
  float x0 = b2f(p[lane]) * TEMP_ISQ, x1 = b2f(p[lane + 64]) * TEMP_ISQ;
  float mx = fmaxf(x0, x1);
  #pragma unroll
  for (int o = 32; o; o >>= 1) mx = fmaxf(mx, __shfl_xor(mx, o));
  float e0 = expf(x0 - mx), e1 = expf(x1 - mx);
  float s = e0 + e1;
  #pragma unroll
  for (int o = 32; o; o >>= 1) s += __shfl_xor(s, o);
  float inv = 1.f / s;
  P[gw * 128 + lane] = f2b(e0 * inv);
  P[gw * 128 + lane + 64] = f2b(e1 * inv);
}

// ================= routing (fused) =================
__global__ __launch_bounds__(256)
void colmean_apool(const float* __restrict__ colPart, const float* __restrict__ aggF,
                   float* __restrict__ Apool) {
  int b = blockIdx.x, t = threadIdx.x, lane = t & 63, w = t >> 6;
  __shared__ float em[1024];
  float4 s = make_float4(0.f, 0.f, 0.f, 0.f);
  const float4* cp = (const float4*)colPart + (i64)b * 64 * 256 + t;
  for (int lc = 0; lc < 64; ++lc) {
    float4 v = cp[lc * 256];
    s.x += v.x; s.y += v.y; s.z += v.z; s.w += v.w;
  }
  em[t * 4 + 0] = s.x * (1.f / 1024.f); em[t * 4 + 1] = s.y * (1.f / 1024.f);
  em[t * 4 + 2] = s.z * (1.f / 1024.f); em[t * 4 + 3] = s.w * (1.f / 1024.f);
  __syncthreads();
  for (int k = w; k < 128; k += 4) {
    const float* ag = aggF + ((i64)b * 128 + k) * 1024;
    float d = 0.f;
    #pragma unroll
    for (int j = 0; j < 16; ++j) { int e = j * 64 + lane; d += em[e] * ag[e]; }
    #pragma unroll
    for (int o = 32; o; o >>= 1) d += __shfl_down(d, o);
    if (!lane) Apool[b * 128 + k] = d;
  }
}

__global__ __launch_bounds__(256)
void route_rb(const float* __restrict__ Apool, const float* __restrict__ aggF,
              const float* __restrict__ eleW, const float* __restrict__ eleb,
              float* __restrict__ rbv) {
  int b = blockIdx.x, t = threadIdx.x;
  __shared__ float Ap[128];
  if (t < 128) Ap[t] = Apool[b * 128 + t];
  __syncthreads();
  float4 r = make_float4(0.f, 0.f, 0.f, 0.f);
  const float4* ag = (const float4*)(aggF + (i64)b * 128 * 1024) + t;
  #pragma unroll 8
  for (int k = 0; k < 128; ++k) {
    float a = Ap[k];
    float4 v = ag[(i64)k * 256];
    r.x += a * v.x; r.y += a * v.y; r.z += a * v.z; r.w += a * v.w;
  }
  float4 w4 = ((const float4*)(eleW + 1024))[t];
  float d = r.x * w4.x + r.y * w4.y + r.z * w4.z + r.w * w4.w;
  __shared__ float red[256];
  red[t] = d; __syncthreads();
  for (int o = 128; o > 0; o >>= 1) { if (t < o) red[t] += red[t + o]; __syncthreads(); }
  if (t == 0) rbv[b] = red[0] + eleb[0];
}

// ================= gate / final =================
__global__ void gate_kernel(const float* __restrict__ O, float* __restrict__ gate) {
  int b = blockIdx.x, t = threadIdx.x;  // 128 threads
  __shared__ float red[128];
  __shared__ float rd[3];
  for (int i = 0; i < 3; ++i) {
    const float* op = O + ((i64)(b * 3 + i) * 1024) * 32 + 28 + i;
    float s = 0.f;
    #pragma unroll
    for (int l = t; l < 1024; l += 128) s += op[(i64)l * 32];
    red[t] = s; __syncthreads();
    for (int o = 64; o > 0; o >>= 1) { if (t < o) red[t] += red[t + o]; __syncthreads(); }
    if (t == 0) rd[i] = red[0];
    __syncthreads();
  }
  if (t == 0) {
    float m = fmaxf(rd[0], fmaxf(rd[1], rd[2]));
    float e0 = expf(rd[0] - m), e1 = expf(rd[1] - m), e2 = expf(rd[2] - m);
    float inv = 1.f / (e0 + e1 + e2);
    gate[b * 3 + 0] = e0 * inv; gate[b * 3 + 1] = e1 * inv; gate[b * 3 + 2] = e2 * inv;
  }
}

__global__ __launch_bounds__(256)
void final_kernel(const unsigned short* __restrict__ emoB, const float* __restrict__ dotE,
                  const float* __restrict__ rbv, const float* __restrict__ O,
                  const float* __restrict__ gate, float* __restrict__ out) {
  i64 bl = blockIdx.x;
  int b = (int)(bl >> 10), l = (int)(bl & 1023);
  __shared__ float Gg[16];
  int t = threadIdx.x;
  if (t < 16) {
    float g0 = gate[b * 3], g1 = gate[b * 3 + 1], g2 = gate[b * 3 + 2];
    float o0 = O[((i64)(b * 3 + 0) * 1024 + l) * 32 + (t >> 2)];
    float o1 = O[((i64)(b * 3 + 1) * 1024 + l) * 32 + 4 + (t >> 1)];
    float o2 = O[((i64)(b * 3 + 2) * 1024 + l) * 32 + 12 + t];
    Gg[t] = g0 * o0 + g1 * o1 + g2 * o2;
  }
  __syncthreads();
  float re = tanhf(dotE[bl] + rbv[b]);
  ushort4 e4 = ((const ushort4*)(emoB + bl * 1024))[t];
  float g = 1.f + re * Gg[t >> 4];
  ((float4*)(out + bl * 1024))[t] =
      make_float4(b2f(e4.x) * g, b2f(e4.y) * g, b2f(e4.z) * g, b2f(e4.w) * g);
}

// ================= launcher =================
extern "C" void kernel_launch(void* const* d_in, const int* in_sizes, int n_in,
                              void* d_out, int out_size, void* d_ws, size_t ws_size,
                              hipStream_t stream) {
  const float* emo     = (const float*)d_in[0];
  const float* phr     = (const float*)d_in[1];
  const float* video   = (const float*)d_in[2];
  const float* w_v_W   = (const float*)d_in[3];
  const float* w_v_b   = (const float*)d_in[4];
  const float* agg_a_W = (const float*)d_in[5];
  const float* agg_a_b = (const float*)d_in[6];
  const float* agg_c_W = (const float*)d_in[7];
  const float* agg_c_b = (const float*)d_in[8];
  const float* ele_W   = (const float*)d_in[9];
  const float* ele_b   = (const float*)d_in[10];
  const float* wq_W    = (const float*)d_in[11];
  const float* wq_b    = (const float*)d_in[12];
  const float* wk_W    = (const float*)d_in[13];
  const float* wk_b    = (const float*)d_in[14];
  const float* wv_W    = (const float*)d_in[15];
  const float* wv_b    = (const float*)d_in[16];
  const float* wr_W    = (const float*)d_in[17];
  const float* wr_b    = (const float*)d_in[18];

  char* ws = (char*)d_ws;
  // ---- region map (bytes) ----
  const i64 oEmoB    = 0;            // ushort [32,1024,1024] 67,108,864 (live to end)
  const i64 oPooled  = 67108864;     // pooledCat: pooled [32,256,1024] + videoB [32,256,1024]
  const i64 oVideoB  = 83886080;     //   (dead after logits gemm)
  const i64 oP       = 67108864;     //   overlay: ushort [96,1024,128] (PL writes, in-place softmax)
  const i64 oWvB     = 100663296;    // ushort [1024,1024] 2,097,152 (dead after W3cat gemm)
  const i64 oW3cat   = 102760448;    // ushort [1152,1024] 2,359,296: W3 rows 0..1023, A2T rows 1024..1151
  const i64 oAggF    = 100663296;    //   overlay: float [32,128,1024] (G4 writes; dead after route_rb)
  const i64 oO       = 100663296;    //   overlay: float [96,1024,32] (OV writes)
  const i64 oCT      = 117440512;    // ushort [32,1024,512] 33,554,432 (dead after G4)
  const i64 oW2T     = 117440512;    //   overlay: ushort [96,128,1024]
  const i64 oAttnAT  = 150994944;    // ushort [32,128,512] 4,194,304
  const i64 oAggB    = 155189248;    // ushort [32,128,1024] 8,388,608
  const i64 oAcaT    = 165675008;    // ushort: acT [1024,1024] + aaT [128,1024] = 2,359,296
  const i64 oWqB     = 168034304;    // ushort [1024,448]
  const i64 oKvrT    = 169082880;    // 1,048,576
  const i64 oKVR     = 170131456;    // ushort [32,128,480] 3,932,160
  const i64 oVT      = 174063616;    // ushort [32,128,128] 1,048,576
  const i64 oBias    = 175112192;    // kvrB[480]@+0, cbrow[1024]@+2048, ab2[128]@+6144
  const i64 oColPart = 175247360;    // float [32,64,1024] 8,388,608
  const i64 oDotE    = 183635968;    // 131,072
  const i64 oApool   = 183767040;    // 16,384
  const i64 oQb      = 183783424;    // float [96,128] 49,152
  const i64 oRb      = 183914496;    // 256
  const i64 oGate    = 184307968;    // 512

  unsigned short* emoB    = (unsigned short*)(ws + oEmoB);
  unsigned short* pooled  = (unsigned short*)(ws + oPooled);   // pooledCat base (64 batches)
  unsigned short* videoB  = (unsigned short*)(ws + oVideoB);
  unsigned short* P       = (unsigned short*)(ws + oP);
  unsigned short* wvB     = (unsigned short*)(ws + oWvB);
  unsigned short* W3      = (unsigned short*)(ws + oW3cat);
  unsigned short* A2T     = W3 + (i64)1024 * 1024;
  float*          aggF    = (float*)(ws + oAggF);
  float*          O       = (float*)(ws + oO);
  unsigned short* CT      = (unsigned short*)(ws + oCT);
  unsigned short* W2T     = (unsigned short*)(ws + oW2T);
  unsigned short* attnAT  = (unsigned short*)(ws + oAttnAT);
  unsigned short* aggB    = (unsigned short*)(ws + oAggB);
  unsigned short* acT     = (unsigned short*)(ws + oAcaT);
  unsigned short* aaT     = acT + (i64)1024 * 1024;
  unsigned short* wqB     = (unsigned short*)(ws + oWqB);
  unsigned short* kvrT    = (unsigned short*)(ws + oKvrT);
  unsigned short* KVR     = (unsigned short*)(ws + oKVR);
  unsigned short* VT      = (unsigned short*)(ws + oVT);
  float*          kvrB    = (float*)(ws + oBias);
  float*          cbrow   = (float*)(ws + oBias + 2048);
  float*          ab2     = (float*)(ws + oBias + 6144);
  float*          colPart = (float*)(ws + oColPart);
  float*          dotE    = (float*)(ws + oDotE);
  float*          Apool   = (float*)(ws + oApool);
  float*          qb      = (float*)(ws + oQb);
  float*          rbv     = (float*)(ws + oRb);
  float*          gate    = (float*)(ws + oGate);

  dim3 blk(256);

  // fused emo pass: colPart + dotE + emoB
  emo_pass1<<<dim3(64, 32), blk, 0, stream>>>(emo, ele_W, emoB, colPart, dotE);

  // weight prep + bias folds
  transpose_all<<<dim3(98, 32), blk, 0, stream>>>(agg_a_W, agg_c_W, wq_W, w_v_W,
                                                  wk_W, wv_W, wr_W, aaT, acT, wqB, wvB, kvrT);
  bias_prep<<<7, blk, 0, stream>>>(wk_b, wv_b, wr_b, agg_c_W, agg_c_b,
                                   agg_a_W, agg_a_b, w_v_b, kvrB, cbrow, ab2);

  // pooled + videoB bf16
  pv_conv<<<16384, blk, 0, stream>>>(phr, video, pooled, videoB);

  // W3cat[1152,1024] = [acT; aaT] @ wvB^T  (rows 0..1023 = W3, 1024..1151 = A2T)
  gemm_mfma<0, 1, 0, 1><<<dim3(8, 9, 1), blk, 0, stream>>>(acT, 0, wvB, 0,
      nullptr, nullptr, nullptr, nullptr, (void*)W3, 0, nullptr, 0,
      1024, 1024, 1024, 1024, 1024, nullptr, 0, nullptr);

  // CT (z-packed): z<32: W3 @ pooled^T + cbrow -> cols 0..255;
  //                z>=32: acT @ videoB^T + agg_c_b -> cols 256..511
  gemm_mfma<2, 1, 0, 1, 6><<<dim3(2, 8, 64), blk, 0, stream>>>(W3, 0, pooled, 262144,
      acT, nullptr, cbrow, agg_c_b, (void*)CT, 524288, nullptr, 0,
      256, 1024, 1024, 1024, 512, nullptr, 0, nullptr);

  // attn logits (z-packed) + softmax epilogue -> attnAT (bf16, transposed)
  gemm_mfma<1, 1, 0, 1, 5, 2><<<dim3(1, 2, 64), blk, 0, stream>>>(pooled, 262144, A2T, 0,
      nullptr, aaT, ab2, agg_a_b, (void*)attnAT, 65536, nullptr, 0,
      128, 1024, 1024, 1024, 512, nullptr, 0, nullptr);

  // G4: agg = attnAT @ CT^T (fp32 + bf16)
  gemm_mfma<0, 2, 0, 1><<<dim3(8, 1, 32), blk, 0, stream>>>(attnAT, 65536, CT, 524288,
      nullptr, nullptr, nullptr, nullptr, (void*)aggF, 131072, aggB, 131072,
      1024, 512, 512, 512, 1024, nullptr, 0, nullptr);

  // element routing (fp32, fused)
  colmean_apool<<<32, blk, 0, stream>>>(colPart, aggF, Apool);
  route_rb<<<32, blk, 0, stream>>>(Apool, aggF, ele_W, ele_b, rbv);

  // KVR = agg @ [wk|wv|wr] + bias
  gemm_mfma<1, 1, 0, 1><<<dim3(4, 1, 32), blk, 0, stream>>>(aggB, 131072, kvrT, 0,
      nullptr, nullptr, kvrB, nullptr, (void*)KVR, 61440, nullptr, 0,
      480, 1024, 1024, 1024, 480, nullptr, 0, nullptr);
  vtq_fill<<<dim3(67, 32), blk, 0, stream>>>(KVR, wq_b, VT, qb);

  // W2T[z=(b,i)] = K_i[b] @ wq_i^T  (bf16)
  gemm_mfma<0, 1, 0, 1, 3><<<dim3(8, 1, 96), blk, 0, stream>>>(KVR, 61440, wqB, 0,
      nullptr, nullptr, nullptr, nullptr, (void*)W2T, 131072, nullptr, 0,
      1024, 0, 480, 448, 1024, nullptr, 0, nullptr);

  // PL = tanh(dotE+rb) * (emoB @ W2T^T) + qb  (bf16 logits)
  gemm_mfma<1, 1, 1, 1, 2><<<dim3(1, 8, 96), blk, 0, stream>>>(emoB, 1048576, W2T, 131072,
      nullptr, nullptr, qb, nullptr, (void*)P, 131072, nullptr, 0,
      128, 1024, 1024, 1024, 128, dotE, 1024, rbv);

  softmax_P_bf<<<24576, blk, 0, stream>>>(P, P);

  // OV: O[:, :28] = tanh((P @ VT^T)/3); O[:, 28..30] = (P @ R)/1024
  gemm_mfma<0, 4, 0, 3><<<dim3(1, 8, 96), blk, 0, stream>>>(P, 131072, VT, 16384,
      nullptr, nullptr, nullptr, nullptr, (void*)O, 32768, nullptr, 0,
      31, 128, 128, 128, 32, nullptr, 0, nullptr);

  gate_kernel<<<32, 128, 0, stream>>>(O, gate);
  final_kernel<<<32768, blk, 0, stream>>>(emoB, dotE, rbv, O, gate, (float*)d_out);
}

// Round 10
// 458.083 us; speedup vs baseline: 1.0512x; 1.0512x over previous
//
#include <hip/hip_runtime.h>
#include <math.h>

typedef long long i64;
typedef __attribute__((ext_vector_type(8))) short bf16x8;
typedef __attribute__((ext_vector_type(4))) float f32x4;

#define TEMP_ISQ 0.047245559f   // 1/sqrt(448)

__device__ __forceinline__ unsigned short f2b(float x) {
  union { float f; unsigned u; } a; a.f = x;
  return (unsigned short)((a.u + 0x7fffu + ((a.u >> 16) & 1u)) >> 16);
}
__device__ __forceinline__ float b2f(unsigned short b) {
  union { float f; unsigned u; } a; a.u = ((unsigned)b) << 16; return a.f;
}

// ================= NT bf16 MFMA GEMM =================
// out[M,N] = A[M,K] @ BT[N,K]^T (+bias). 128x128 tile, BK=32 double-buffered,
// ONE barrier per K-step. T1 chunked XCD swizzle (nwg % 8 == 0). LDS slot XOR
// f(r)=(r>>1)&3 on BOTH staged source and ds_read (rule #21, round-3-proven).
// BIAS: 0 none, 1 col bias, 2 row bias
// OUTM: 0 fp32, 1 bf16, 2 both (fp32 Ob + bf16 O2b),
//       4 fp32: col<28 tanh(acc/3), col 28..30 acc/1024 (OV+Rdiag fusion)
// RS:   1 -> v *= tanhf(rowScale[zA*sRS + row] + rsAdd[zA])
// BZDIV: B batch index = z / BZDIV (XMODE 0)
// XMODE: 0 normal; 2 PL (zA=z/3: A per zA, B per z, col-bias per z);
//        3 W2T (z->(b,i): A=KVR+b*sA+doff_i, B=wqB+doff_i, Kd=d_i)
template<int BIAS, int OUTM, int RS, int BZDIV, int XMODE = 0>
__global__ __launch_bounds__(256)
void gemm_mfma(const unsigned short* __restrict__ Ab, i64 sA,
               const unsigned short* __restrict__ Bb, i64 sB,
               const float* __restrict__ bias,
               void* __restrict__ Ob, i64 sO,
               unsigned short* __restrict__ O2b, i64 sO2,
               int Nn, int Kd, int ldA, int ldB, int ldO,
               const float* __restrict__ rowScale, i64 sRS,
               const float* __restrict__ rsAdd)
{
  __shared__ unsigned short As[2][4096];
  __shared__ unsigned short Bs[2][4096];
  const int tid = threadIdx.x;
  const int w = tid >> 6, lane = tid & 63;

  // T1 chunked XCD swizzle
  const int gx = gridDim.x, gy = gridDim.y;
  int nwg = gx * gy * gridDim.z;
  int bid = blockIdx.x + gx * (blockIdx.y + gy * blockIdx.z);
  int L = bid;
  if ((nwg & 7) == 0) L = (bid & 7) * (nwg >> 3) + (bid >> 3);
  const int bx = L % gx;
  int rem = L / gx;
  const int by = rem % gy;
  const int z  = rem / gy;

  const int m0 = by * 128, n0 = bx * 128;
  int zA = (XMODE == 2) ? z / 3 : z;
  const unsigned short* A;
  const unsigned short* B;
  int KdL = Kd;
  if (XMODE == 3) {
    int bb = z / 3, ii = z - bb * 3;
    const int dof_[3] = {0, 256, 384};
    const int kdt_[3] = {256, 128, 64};
    A = Ab + (i64)bb * sA + dof_[ii];
    B = Bb + dof_[ii];
    KdL = kdt_[ii];
  } else if (XMODE == 2) {
    A = Ab + (i64)zA * sA;
    B = Bb + (i64)z * sB;
  } else {
    A = Ab + (i64)z * sA;
    B = Bb + (i64)(BZDIV == 1 ? z : z / BZDIV) * sB;
  }
  const int wr = w >> 1, wc = w & 1;
  const int rS = tid >> 2, sS = tid & 3;
  const int cL = lane & 15, sl = lane >> 4;

  f32x4 acc[4][4];
  #pragma unroll
  for (int i = 0; i < 4; ++i)
    #pragma unroll
    for (int j = 0; j < 4; ++j) acc[i][j] = (f32x4){0.f, 0.f, 0.f, 0.f};

  auto STAGE = [&](int buf, int k0) {
    #pragma unroll
    for (int q = 0; q < 2; ++q) {
      int r = rS + q * 64;
      int sg = sS ^ ((r >> 1) & 3);
      const unsigned short* sa = A + (i64)(m0 + r) * ldA + k0 + sg * 8;
      const unsigned short* sb = B + (i64)(n0 + r) * ldB + k0 + sg * 8;
      __builtin_amdgcn_global_load_lds(
          (__attribute__((address_space(1))) void*)sa,
          (__attribute__((address_space(3))) void*)&As[buf][r * 32 + sS * 8], 16, 0, 0);
      __builtin_amdgcn_global_load_lds(
          (__attribute__((address_space(1))) void*)sb,
          (__attribute__((address_space(3))) void*)&Bs[buf][r * 32 + sS * 8], 16, 0, 0);
    }
  };

  STAGE(0, 0);
  __syncthreads();

  for (int k0 = 0; k0 < KdL; k0 += 32) {
    const int cur = (k0 >> 5) & 1;
    if (k0 + 32 < KdL) STAGE(cur ^ 1, k0 + 32);   // prefetch flies under compute
    bf16x8 af[4], bfv[4];
    #pragma unroll
    for (int mi = 0; mi < 4; ++mi) {
      int rr = wr * 64 + mi * 16 + cL;
      int ph = sl ^ ((rr >> 1) & 3);
      af[mi] = *(const bf16x8*)&As[cur][rr * 32 + ph * 8];
    }
    #pragma unroll
    for (int ni = 0; ni < 4; ++ni) {
      int rr = wc * 64 + ni * 16 + cL;
      int ph = sl ^ ((rr >> 1) & 3);
      bfv[ni] = *(const bf16x8*)&Bs[cur][rr * 32 + ph * 8];
    }
    #pragma unroll
    for (int mi = 0; mi < 4; ++mi)
      #pragma unroll
      for (int ni = 0; ni < 4; ++ni)
        acc[mi][ni] = __builtin_amdgcn_mfma_f32_16x16x32_bf16(af[mi], bfv[ni], acc[mi][ni], 0, 0, 0);
    __syncthreads();
  }

  // D layout: col=lane&15, row=(lane>>4)*4+reg
  const float* bp = (XMODE == 2) ? (bias + (i64)z * 128) : bias;
  #pragma unroll
  for (int mi = 0; mi < 4; ++mi) {
    const int rowb = m0 + wr * 64 + mi * 16 + sl * 4;
    #pragma unroll
    for (int ni = 0; ni < 4; ++ni) {
      const int col = n0 + wc * 64 + ni * 16 + cL;
      if (col < Nn) {
        float bc = (BIAS == 1) ? bp[col] : 0.f;
        #pragma unroll
        for (int rg = 0; rg < 4; ++rg) {
          float v = acc[mi][ni][rg];
          if (RS) v *= tanhf(rowScale[(i64)zA * sRS + rowb + rg] + rsAdd[zA]);
          v += bc;
          if (BIAS == 2) v += bias[rowb + rg];
          i64 oidx = (i64)(rowb + rg) * ldO + col;
          if (OUTM == 0)      ((float*)Ob)[(i64)z * sO + oidx] = v;
          else if (OUTM == 1) ((unsigned short*)Ob)[(i64)z * sO + oidx] = f2b(v);
          else if (OUTM == 4) {
            float ov = (col < 28) ? tanhf(v * (1.f / 3.f)) : v * (1.f / 1024.f);
            ((float*)Ob)[(i64)z * sO + oidx] = ov;
          } else {
            ((float*)Ob)[(i64)z * sO + oidx] = v;
            O2b[(i64)z * sO2 + oidx] = f2b(v);
          }
        }
      }
    }
  }
}

// ================= fused emo pass =================
__global__ __launch_bounds__(256)
void emo_pass1(const float* __restrict__ emo, const float* __restrict__ eleW,
               unsigned short* __restrict__ emoB, float* __restrict__ colPart,
               float* __restrict__ dotE) {
  int b = blockIdx.y, lc = blockIdx.x;   // 64 chunks x 16 rows
  int t = threadIdx.x, lane = t & 63, w = t >> 6;
  float4 w4 = ((const float4*)eleW)[t];
  float4 acc = make_float4(0.f, 0.f, 0.f, 0.f);
  __shared__ float dw[16][4];
  const float4* src = (const float4*)emo + ((i64)b * 1024 + lc * 16) * 256;
  ushort4* dst = (ushort4*)emoB + ((i64)b * 1024 + lc * 16) * 256;
  #pragma unroll 4
  for (int lr = 0; lr < 16; ++lr) {
    float4 v = src[lr * 256 + t];
    acc.x += v.x; acc.y += v.y; acc.z += v.z; acc.w += v.w;
    float d = v.x * w4.x + v.y * w4.y + v.z * w4.z + v.w * w4.w;
    #pragma unroll
    for (int o = 32; o; o >>= 1) d += __shfl_xor(d, o);
    if (!lane) dw[lr][w] = d;
    ushort4 o4; o4.x = f2b(v.x); o4.y = f2b(v.y); o4.z = f2b(v.z); o4.w = f2b(v.w);
    dst[lr * 256 + t] = o4;
  }
  __syncthreads();
  if (t < 16) dotE[(i64)b * 1024 + lc * 16 + t] = dw[t][0] + dw[t][1] + dw[t][2] + dw[t][3];
  ((float4*)colPart)[((i64)b * 64 + lc) * 256 + t] = acc;
}

// ================= prep kernels =================
// 6 weight transposes + wq bf16 convert, one launch. grid (98, 32).
__global__ __launch_bounds__(256)
void transpose_all(const float* __restrict__ w_v_W, const float* __restrict__ agg_a_W,
                   const float* __restrict__ agg_c_W, const float* __restrict__ wq_W,
                   const float* __restrict__ wk_W, const float* __restrict__ wv_W,
                   const float* __restrict__ wr_W,
                   unsigned short* __restrict__ wvT, unsigned short* __restrict__ aaT,
                   unsigned short* __restrict__ acT, unsigned short* __restrict__ wqB,
                   unsigned short* __restrict__ kvrT) {
  int bx = blockIdx.x;
  int t = threadIdx.x;
  if (bx >= 84) {   // wqB: fp32->bf16 convert of wq_W [1024x448]
    i64 li = (((i64)(bx - 84) * 32 + blockIdx.y) * 256 + t) * 4;
    float4 v = *(const float4*)(wq_W + li);
    ushort4 o; o.x = f2b(v.x); o.y = f2b(v.y); o.z = f2b(v.z); o.w = f2b(v.w);
    *(ushort4*)(wqB + li) = o;
    return;
  }
  __shared__ float T[32][33];
  const float* in; unsigned short* out; int N, Npad, s0;
  if (bx < 32)      { in = w_v_W;   out = wvT;                     N = 1024; Npad = 1024; s0 = 0; }
  else if (bx < 36) { in = agg_a_W; out = aaT;                     N = 128;  Npad = 128;  s0 = 32; }
  else if (bx < 68) { in = agg_c_W; out = acT;                     N = 1024; Npad = 1024; s0 = 36; }
  else if (bx < 82) { in = wk_W;    out = kvrT;                    N = 448;  Npad = 448;  s0 = 68; }
  else if (bx < 83) { in = wv_W;    out = kvrT + (i64)448 * 1024;  N = 28;   Npad = 28;   s0 = 82; }
  else              { in = wr_W;    out = kvrT + (i64)476 * 1024;  N = 3;    Npad = 36;   s0 = 83; }
  int n0 = (bx - s0) * 32, k0 = blockIdx.y * 32;
  #pragma unroll
  for (int p = 0; p < 4; ++p) {
    int idx = t + 256 * p; int kk = idx >> 5, nn = idx & 31;
    float v = 0.f;
    if (n0 + nn < N) v = in[(i64)(k0 + kk) * N + (n0 + nn)];
    T[nn][kk] = v;
  }
  __syncthreads();
  #pragma unroll
  for (int p = 0; p < 4; ++p) {
    int idx = t + 256 * p; int nn = idx >> 5, kk = idx & 31;
    if (n0 + nn < Npad) out[(i64)(n0 + nn) * 1024 + (k0 + kk)] = f2b(T[nn][kk]);
  }
}

__global__ void kvr_bias_kernel(const float* wkb, const float* wvb, const float* wrb, float* out) {
  int t = blockIdx.x * 256 + threadIdx.x;
  if (t >= 480) return;
  out[t] = (t < 448) ? wkb[t] : (t < 476) ? wvb[t - 448] : (t < 479) ? wrb[t - 476] : 0.f;
}

// fused pool_phr + vconv (grid 16384): pooled bf16 + combine rows 256..511
__global__ void pv_conv(const float* __restrict__ phr, const float* __restrict__ video,
                        unsigned short* __restrict__ pooled, unsigned short* __restrict__ combine) {
  i64 idx = (i64)blockIdx.x * 256 + threadIdx.x;
  if (idx < 2097152) {
    i64 bm = idx >> 8; int c = (int)(idx & 255);
    i64 b = bm >> 8, m = bm & 255;
    const float4* r0 = (const float4*)(phr + (b * 512 + 2 * m) * 1024) + c;
    const float4* r1 = (const float4*)(phr + (b * 512 + 2 * m + 1) * 1024) + c;
    float4 a = *r0, d = *r1;
    ushort4 o;
    o.x = f2b(0.5f * (a.x + d.x)); o.y = f2b(0.5f * (a.y + d.y));
    o.z = f2b(0.5f * (a.z + d.z)); o.w = f2b(0.5f * (a.w + d.w));
    ((ushort4*)pooled)[idx] = o;
  } else {
    i64 j = idx - 2097152;
    i64 b = j >> 16, r = j & 65535;
    float4 v = ((const float4*)video)[j];
    ushort4 o;
    o.x = f2b(v.x); o.y = f2b(v.y); o.z = f2b(v.z); o.w = f2b(v.w);
    ((ushort4*)combine)[b * 131072 + 65536 + r] = o;
  }
}

// fused vt_fill (V rows 0..27, R rows 28..30, pad to 128) and qb. grid (67, 32).
__global__ void vtq_fill(const unsigned short* __restrict__ KVR, const float* __restrict__ wq_b,
                         unsigned short* __restrict__ VT, float* __restrict__ qb) {
  int b = blockIdx.y, bx = blockIdx.x, t = threadIdx.x;
  if (bx < 64) {
    int idx = bx * 256 + t;
    int n = idx >> 7, k = idx & 127;
    unsigned short v = 0;
    if (n < 28)      v = KVR[(i64)b * 61440 + k * 480 + 448 + n];
    else if (n < 31) v = KVR[(i64)b * 61440 + k * 480 + 476 + (n - 28)];
    VT[((i64)b * 128 + n) * 128 + k] = v;
  } else if (t < 128) {
    int ii = bx - 64;
    const int dof_[3] = {0, 256, 384};
    const int kdt_[3] = {256, 128, 64};
    const unsigned short* kp = KVR + (i64)b * 61440 + t * 480 + dof_[ii];
    const float* wb = wq_b + dof_[ii];
    float s = 0.f;
    for (int d = 0; d < kdt_[ii]; ++d) s += b2f(kp[d]) * wb[d];
    qb[(b * 3 + ii) * 128 + t] = s;
  }
}

// ================= softmax =================
__global__ void softmax_attn_a(const float* __restrict__ logits, unsigned short* __restrict__ outT) {
  int gw = (int)(((i64)blockIdx.x * blockDim.x + threadIdx.x) >> 6);
  int lane = threadIdx.x & 63;
  if (gw >= 32 * 512) return;
  int b = gw >> 9, m = gw & 511;
  const float* p = logits + (i64)gw * 128;
  float x0 = p[lane], x1 = p[lane + 64];
  float mx = fmaxf(x0, x1);
  #pragma unroll
  for (int o = 32; o; o >>= 1) mx = fmaxf(mx, __shfl_xor(mx, o));
  float e0 = expf(x0 - mx), e1 = expf(x1 - mx);
  float s = e0 + e1;
  #pragma unroll
  for (int o = 32; o; o >>= 1) s += __shfl_xor(s, o);
  float inv = 1.f / s;
  unsigned short* o0 = outT + (i64)b * 128 * 512 + m;
  o0[(i64)lane * 512] = f2b(e0 * inv);
  o0[(i64)(lane + 64) * 512] = f2b(e1 * inv);
}

// in-place: each warp owns one row of PL
__global__ void softmax_P_bf(const unsigned short* __restrict__ PL, unsigned short* __restrict__ P) {
  i64 gw = ((i64)blockIdx.x * blockDim.x + threadIdx.x) >> 6;
  int lane = threadIdx.x & 63;
  if (gw >= 98304) return;
  const unsigned short* p = PL + gw * 128;
  float x0 = b2f(p[lane]) * TEMP_ISQ, x1 = b2f(p[lane + 64]) * TEMP_ISQ;
  float mx = fmaxf(x0, x1);
  #pragma unroll
  for (int o = 32; o; o >>= 1) mx = fmaxf(mx, __shfl_xor(mx, o));
  float e0 = expf(x0 - mx), e1 = expf(x1 - mx);
  float s = e0 + e1;
  #pragma unroll
  for (int o = 32; o; o >>= 1) s += __shfl_xor(s, o);
  float inv = 1.f / s;
  P[gw * 128 + lane] = f2b(e0 * inv);
  P[gw * 128 + lane + 64] = f2b(e1 * inv);
}

// ================= routing (fused) =================
__global__ __launch_bounds__(256)
void colmean_apool(const float* __restrict__ colPart, const float* __restrict__ aggF,
                   float* __restrict__ Apool) {
  int b = blockIdx.x, t = threadIdx.x, lane = t & 63, w = t >> 6;
  __shared__ float em[1024];
  float4 s = make_float4(0.f, 0.f, 0.f, 0.f);
  const float4* cp = (const float4*)colPart + (i64)b * 64 * 256 + t;
  for (int lc = 0; lc < 64; ++lc) {
    float4 v = cp[lc * 256];
    s.x += v.x; s.y += v.y; s.z += v.z; s.w += v.w;
  }
  em[t * 4 + 0] = s.x * (1.f / 1024.f); em[t * 4 + 1] = s.y * (1.f / 1024.f);
  em[t * 4 + 2] = s.z * (1.f / 1024.f); em[t * 4 + 3] = s.w * (1.f / 1024.f);
  __syncthreads();
  for (int k = w; k < 128; k += 4) {
    const float* ag = aggF + ((i64)b * 128 + k) * 1024;
    float d = 0.f;
    #pragma unroll
    for (int j = 0; j < 16; ++j) { int e = j * 64 + lane; d += em[e] * ag[e]; }
    #pragma unroll
    for (int o = 32; o; o >>= 1) d += __shfl_down(d, o);
    if (!lane) Apool[b * 128 + k] = d;
  }
}

__global__ __launch_bounds__(256)
void route_rb(const float* __restrict__ Apool, const float* __restrict__ aggF,
              const float* __restrict__ eleW, const float* __restrict__ eleb,
              float* __restrict__ rbv) {
  int b = blockIdx.x, t = threadIdx.x;
  __shared__ float Ap[128];
  if (t < 128) Ap[t] = Apool[b * 128 + t];
  __syncthreads();
  float4 r = make_float4(0.f, 0.f, 0.f, 0.f);
  const float4* ag = (const float4*)(aggF + (i64)b * 128 * 1024) + t;
  #pragma unroll 8
  for (int k = 0; k < 128; ++k) {
    float a = Ap[k];
    float4 v = ag[(i64)k * 256];
    r.x += a * v.x; r.y += a * v.y; r.z += a * v.z; r.w += a * v.w;
  }
  float4 w4 = ((const float4*)(eleW + 1024))[t];
  float d = r.x * w4.x + r.y * w4.y + r.z * w4.z + r.w * w4.w;
  __shared__ float red[256];
  red[t] = d; __syncthreads();
  for (int o = 128; o > 0; o >>= 1) { if (t < o) red[t] += red[t + o]; __syncthreads(); }
  if (t == 0) rbv[b] = red[0] + eleb[0];
}

// ================= gate / final =================
__global__ void gate_kernel(const float* __restrict__ O, float* __restrict__ gate) {
  int b = blockIdx.x, t = threadIdx.x;  // 128 threads
  __shared__ float red[128];
  __shared__ float rd[3];
  for (int i = 0; i < 3; ++i) {
    const float* op = O + ((i64)(b * 3 + i) * 1024) * 32 + 28 + i;
    float s = 0.f;
    #pragma unroll
    for (int l = t; l < 1024; l += 128) s += op[(i64)l * 32];
    red[t] = s; __syncthreads();
    for (int o = 64; o > 0; o >>= 1) { if (t < o) red[t] += red[t + o]; __syncthreads(); }
    if (t == 0) rd[i] = red[0];
    __syncthreads();
  }
  if (t == 0) {
    float m = fmaxf(rd[0], fmaxf(rd[1], rd[2]));
    float e0 = expf(rd[0] - m), e1 = expf(rd[1] - m), e2 = expf(rd[2] - m);
    float inv = 1.f / (e0 + e1 + e2);
    gate[b * 3 + 0] = e0 * inv; gate[b * 3 + 1] = e1 * inv; gate[b * 3 + 2] = e2 * inv;
  }
}

__global__ __launch_bounds__(256)
void final_kernel(const unsigned short* __restrict__ emoB, const float* __restrict__ dotE,
                  const float* __restrict__ rbv, const float* __restrict__ O,
                  const float* __restrict__ gate, float* __restrict__ out) {
  i64 bl = blockIdx.x;
  int b = (int)(bl >> 10), l = (int)(bl & 1023);
  __shared__ float Gg[16];
  int t = threadIdx.x;
  if (t < 16) {
    float g0 = gate[b * 3], g1 = gate[b * 3 + 1], g2 = gate[b * 3 + 2];
    float o0 = O[((i64)(b * 3 + 0) * 1024 + l) * 32 + (t >> 2)];
    float o1 = O[((i64)(b * 3 + 1) * 1024 + l) * 32 + 4 + (t >> 1)];
    float o2 = O[((i64)(b * 3 + 2) * 1024 + l) * 32 + 12 + t];
    Gg[t] = g0 * o0 + g1 * o1 + g2 * o2;
  }
  __syncthreads();
  float re = tanhf(dotE[bl] + rbv[b]);
  ushort4 e4 = ((const ushort4*)(emoB + bl * 1024))[t];
  float g = 1.f + re * Gg[t >> 4];
  ((float4*)(out + bl * 1024))[t] =
      make_float4(b2f(e4.x) * g, b2f(e4.y) * g, b2f(e4.z) * g, b2f(e4.w) * g);
}

// ================= launcher =================
extern "C" void kernel_launch(void* const* d_in, const int* in_sizes, int n_in,
                              void* d_out, int out_size, void* d_ws, size_t ws_size,
                              hipStream_t stream) {
  const float* emo     = (const float*)d_in[0];
  const float* phr     = (const float*)d_in[1];
  const float* video   = (const float*)d_in[2];
  const float* w_v_W   = (const float*)d_in[3];
  const float* w_v_b   = (const float*)d_in[4];
  const float* agg_a_W = (const float*)d_in[5];
  const float* agg_a_b = (const float*)d_in[6];
  const float* agg_c_W = (const float*)d_in[7];
  const float* agg_c_b = (const float*)d_in[8];
  const float* ele_W   = (const float*)d_in[9];
  const float* ele_b   = (const float*)d_in[10];
  const float* wq_W    = (const float*)d_in[11];
  const float* wq_b    = (const float*)d_in[12];
  const float* wk_W    = (const float*)d_in[13];
  const float* wk_b    = (const float*)d_in[14];
  const float* wv_W    = (const float*)d_in[15];
  const float* wv_b    = (const float*)d_in[16];
  const float* wr_W    = (const float*)d_in[17];
  const float* wr_b    = (const float*)d_in[18];

  char* ws = (char*)d_ws;
  // ---- region map (bytes) ----
  const i64 oEmoB    = 0;            // ushort [32,1024,1024] 67,108,864 (live to end)
  const i64 oCombine = 67108864;     // ushort [32,512,1024] (dead after CT gemm)
  const i64 oP       = 67108864;     //   overlay: ushort [96,1024,128]; softmax IN-PLACE
  const i64 oPooled  = 100663296;    // ushort [32,256,1024] (dead after G1)
  const i64 oLogitsA = 100663296;    //   overlay: float [32,512,128] (dead after softmax_attn_a)
  const i64 oAggF    = 100663296;    //   overlay: float [32,128,1024] (dead after route_rb)
  const i64 oO       = 100663296;    //   overlay: float [96,1024,32] (written by OV)
  const i64 oCT      = 117440512;    // ushort [32,1024,512] (dead after G4)
  const i64 oW2T     = 117440512;    //   overlay: ushort [96,128,1024]
  const i64 oAttnAT  = 150994944;    // ushort [32,128,512] 4,194,304
  const i64 oAggB    = 155189248;    // ushort [32,128,1024] 8,388,608
  const i64 oWvT     = 163577856;    // 2,097,152
  const i64 oAaT     = 165675008;    // 262,144
  const i64 oAcT     = 165937152;    // 2,097,152
  const i64 oWqB     = 168034304;    // ushort [1024,448]
  const i64 oKvrT    = 169082880;    // 1,048,576
  const i64 oKVR     = 170131456;    // ushort [32,128,480] 3,932,160
  const i64 oVT      = 174063616;    // ushort [32,128,128] 1,048,576
  const i64 oKvrB    = 175112192;    // 4,096
  const i64 oColPart = 175247360;    // float [32,64,1024] 8,388,608
  const i64 oDotE    = 183635968;    // 131,072
  const i64 oApool   = 183767040;    // 16,384
  const i64 oQb      = 183783424;    // float [96,128] 49,152
  const i64 oRb      = 183914496;    // 256
  const i64 oGate    = 184307968;    // 512

  unsigned short* emoB    = (unsigned short*)(ws + oEmoB);
  unsigned short* combine = (unsigned short*)(ws + oCombine);
  unsigned short* P       = (unsigned short*)(ws + oP);
  unsigned short* pooled  = (unsigned short*)(ws + oPooled);
  float*          logitsA = (float*)(ws + oLogitsA);
  float*          aggF    = (float*)(ws + oAggF);
  float*          O       = (float*)(ws + oO);
  unsigned short* CT      = (unsigned short*)(ws + oCT);
  unsigned short* W2T     = (unsigned short*)(ws + oW2T);
  unsigned short* attnAT  = (unsigned short*)(ws + oAttnAT);
  unsigned short* aggB    = (unsigned short*)(ws + oAggB);
  unsigned short* wvT     = (unsigned short*)(ws + oWvT);
  unsigned short* aaT     = (unsigned short*)(ws + oAaT);
  unsigned short* acT     = (unsigned short*)(ws + oAcT);
  unsigned short* wqB     = (unsigned short*)(ws + oWqB);
  unsigned short* kvrT    = (unsigned short*)(ws + oKvrT);
  unsigned short* KVR     = (unsigned short*)(ws + oKVR);
  unsigned short* VT      = (unsigned short*)(ws + oVT);
  float*          kvrB    = (float*)(ws + oKvrB);
  float*          colPart = (float*)(ws + oColPart);
  float*          dotE    = (float*)(ws + oDotE);
  float*          Apool   = (float*)(ws + oApool);
  float*          qb      = (float*)(ws + oQb);
  float*          rbv     = (float*)(ws + oRb);
  float*          gate    = (float*)(ws + oGate);

  dim3 blk(256);

  // fused emo pass: colPart + dotE + emoB
  emo_pass1<<<dim3(64, 32), blk, 0, stream>>>(emo, ele_W, emoB, colPart, dotE);

  // weight prep (single launch) + bias pack
  transpose_all<<<dim3(98, 32), blk, 0, stream>>>(w_v_W, agg_a_W, agg_c_W, wq_W, wk_W, wv_W, wr_W,
                                                  wvT, aaT, acT, wqB, kvrT);
  kvr_bias_kernel<<<2, blk, 0, stream>>>(wk_b, wv_b, wr_b, kvrB);

  // feature aggregation
  pv_conv<<<16384, blk, 0, stream>>>(phr, video, pooled, combine);
  gemm_mfma<1, 1, 0, 1><<<dim3(8, 2, 32), blk, 0, stream>>>(pooled, 262144, wvT, 0, w_v_b,
      (void*)combine, 524288, nullptr, 0, 1024, 1024, 1024, 1024, 1024, nullptr, 0, nullptr);
  gemm_mfma<1, 0, 0, 1><<<dim3(1, 4, 32), blk, 0, stream>>>(combine, 524288, aaT, 0, agg_a_b,
      (void*)logitsA, 65536, nullptr, 0, 128, 1024, 1024, 1024, 128, nullptr, 0, nullptr);
  softmax_attn_a<<<4096, blk, 0, stream>>>(logitsA, attnAT);
  gemm_mfma<2, 1, 0, 1><<<dim3(4, 8, 32), blk, 0, stream>>>(acT, 0, combine, 524288, agg_c_b,
      (void*)CT, 524288, nullptr, 0, 512, 1024, 1024, 1024, 512, nullptr, 0, nullptr);
  gemm_mfma<0, 2, 0, 1><<<dim3(8, 1, 32), blk, 0, stream>>>(attnAT, 65536, CT, 524288, nullptr,
      (void*)aggF, 131072, aggB, 131072, 1024, 512, 512, 512, 1024, nullptr, 0, nullptr);

  // element routing (fp32, fused)
  colmean_apool<<<32, blk, 0, stream>>>(colPart, aggF, Apool);
  route_rb<<<32, blk, 0, stream>>>(Apool, aggF, ele_W, ele_b, rbv);

  // KVR = agg @ [wk|wv|wr] + bias
  gemm_mfma<1, 1, 0, 1><<<dim3(4, 1, 32), blk, 0, stream>>>(aggB, 131072, kvrT, 0, kvrB,
      (void*)KVR, 61440, nullptr, 0, 480, 1024, 1024, 1024, 480, nullptr, 0, nullptr);
  vtq_fill<<<dim3(67, 32), blk, 0, stream>>>(KVR, wq_b, VT, qb);

  // W2T[z=(b,i)] = K_i[b] @ wq_i^T  (bf16)
  gemm_mfma<0, 1, 0, 1, 3><<<dim3(8, 1, 96), blk, 0, stream>>>(KVR, 61440, wqB, 0, nullptr,
      (void*)W2T, 131072, nullptr, 0, 1024, 0, 480, 448, 1024, nullptr, 0, nullptr);

  // PL = tanh(dotE+rb) * (emoB @ W2T^T) + qb  (bf16 logits)
  gemm_mfma<1, 1, 1, 1, 2><<<dim3(1, 8, 96), blk, 0, stream>>>(emoB, 1048576, W2T, 131072, qb,
      (void*)P, 131072, nullptr, 0, 128, 1024, 1024, 1024, 128, dotE, 1024, rbv);

  softmax_P_bf<<<24576, blk, 0, stream>>>(P, P);

  // OV: O[:, :28] = tanh((P @ VT^T)/3); O[:, 28..30] = (P @ R)/1024
  gemm_mfma<0, 4, 0, 3><<<dim3(1, 8, 96), blk, 0, stream>>>(P, 131072, VT, 16384, nullptr,
      (void*)O, 32768, nullptr, 0, 31, 128, 128, 128, 32, nullptr, 0, nullptr);

  gate_kernel<<<32, 128, 0, stream>>>(O, gate);
  final_kernel<<<32768, blk, 0, stream>>>(emoB, dotE, rbv, O, gate, (float*)d_out);
}

// Round 11
// 449.727 us; speedup vs baseline: 1.0707x; 1.0186x over previous
//
#include <hip/hip_runtime.h>
#include <math.h>

typedef long long i64;
typedef __attribute__((ext_vector_type(8))) short bf16x8;
typedef __attribute__((ext_vector_type(4))) float f32x4;

#define TEMP_ISQ 0.047245559f   // 1/sqrt(448)

__device__ __forceinline__ unsigned short f2b(float x) {
  union { float f; unsigned u; } a; a.f = x;
  return (unsigned short)((a.u + 0x7fffu + ((a.u >> 16) & 1u)) >> 16);
}
__device__ __forceinline__ float b2f(unsigned short b) {
  union { float f; unsigned u; } a; a.u = ((unsigned)b) << 16; return a.f;
}

// ================= NT bf16 MFMA GEMM =================
// out[M,N] = A[M,K] @ BT[N,K]^T (+bias). 128x128 tile, BK=32 double-buffered,
// ONE barrier per K-step. T1 chunked XCD swizzle (nwg % 8 == 0). LDS slot XOR
// f(r)=(r>>1)&3 on BOTH staged source and ds_read (rule #21, round-3-proven).
// BIAS: 0 none, 1 col bias, 2 row bias, 3 rank-1: v += rowScale[z*sRS+row]*bias[col]
// OUTM: 0 fp32, 1 bf16, 2 both (fp32 Ob + bf16 O2b),
//       4 fp32: col<28 tanh(acc/3), col 28..30 acc/1024 (OV+Rdiag fusion)
// RS:   1 -> v *= tanhf(rowScale[zA*sRS + row] + rsAdd[zA])
// BZDIV: B batch index = z / BZDIV (XMODE 0)
// XMODE: 0 normal; 2 PL (zA=z/3: A per zA, B per z, col-bias per z);
//        3 W2T (z->(b,i): A=KVR+b*sA+doff_i, B=wqB+doff_i, Kd=d_i)
template<int BIAS, int OUTM, int RS, int BZDIV, int XMODE = 0>
__global__ __launch_bounds__(256)
void gemm_mfma(const unsigned short* __restrict__ Ab, i64 sA,
               const unsigned short* __restrict__ Bb, i64 sB,
               const float* __restrict__ bias,
               void* __restrict__ Ob, i64 sO,
               unsigned short* __restrict__ O2b, i64 sO2,
               int Nn, int Kd, int ldA, int ldB, int ldO,
               const float* __restrict__ rowScale, i64 sRS,
               const float* __restrict__ rsAdd)
{
  __shared__ unsigned short As[2][4096];
  __shared__ unsigned short Bs[2][4096];
  const int tid = threadIdx.x;
  const int w = tid >> 6, lane = tid & 63;

  // T1 chunked XCD swizzle
  const int gx = gridDim.x, gy = gridDim.y;
  int nwg = gx * gy * gridDim.z;
  int bid = blockIdx.x + gx * (blockIdx.y + gy * blockIdx.z);
  int L = bid;
  if ((nwg & 7) == 0) L = (bid & 7) * (nwg >> 3) + (bid >> 3);
  const int bx = L % gx;
  int rem = L / gx;
  const int by = rem % gy;
  const int z  = rem / gy;

  const int m0 = by * 128, n0 = bx * 128;
  int zA = (XMODE == 2) ? z / 3 : z;
  const unsigned short* A;
  const unsigned short* B;
  int KdL = Kd;
  if (XMODE == 3) {
    int bb = z / 3, ii = z - bb * 3;
    const int dof_[3] = {0, 256, 384};
    const int kdt_[3] = {256, 128, 64};
    A = Ab + (i64)bb * sA + dof_[ii];
    B = Bb + dof_[ii];
    KdL = kdt_[ii];
  } else if (XMODE == 2) {
    A = Ab + (i64)zA * sA;
    B = Bb + (i64)z * sB;
  } else {
    A = Ab + (i64)z * sA;
    B = Bb + (i64)(BZDIV == 1 ? z : z / BZDIV) * sB;
  }
  const int wr = w >> 1, wc = w & 1;
  const int rS = tid >> 2, sS = tid & 3;
  const int cL = lane & 15, sl = lane >> 4;

  f32x4 acc[4][4];
  #pragma unroll
  for (int i = 0; i < 4; ++i)
    #pragma unroll
    for (int j = 0; j < 4; ++j) acc[i][j] = (f32x4){0.f, 0.f, 0.f, 0.f};

  auto STAGE = [&](int buf, int k0) {
    #pragma unroll
    for (int q = 0; q < 2; ++q) {
      int r = rS + q * 64;
      int sg = sS ^ ((r >> 1) & 3);
      const unsigned short* sa = A + (i64)(m0 + r) * ldA + k0 + sg * 8;
      const unsigned short* sb = B + (i64)(n0 + r) * ldB + k0 + sg * 8;
      __builtin_amdgcn_global_load_lds(
          (__attribute__((address_space(1))) void*)sa,
          (__attribute__((address_space(3))) void*)&As[buf][r * 32 + sS * 8], 16, 0, 0);
      __builtin_amdgcn_global_load_lds(
          (__attribute__((address_space(1))) void*)sb,
          (__attribute__((address_space(3))) void*)&Bs[buf][r * 32 + sS * 8], 16, 0, 0);
    }
  };

  STAGE(0, 0);
  __syncthreads();

  for (int k0 = 0; k0 < KdL; k0 += 32) {
    const int cur = (k0 >> 5) & 1;
    if (k0 + 32 < KdL) STAGE(cur ^ 1, k0 + 32);   // prefetch flies under compute
    bf16x8 af[4], bfv[4];
    #pragma unroll
    for (int mi = 0; mi < 4; ++mi) {
      int rr = wr * 64 + mi * 16 + cL;
      int ph = sl ^ ((rr >> 1) & 3);
      af[mi] = *(const bf16x8*)&As[cur][rr * 32 + ph * 8];
    }
    #pragma unroll
    for (int ni = 0; ni < 4; ++ni) {
      int rr = wc * 64 + ni * 16 + cL;
      int ph = sl ^ ((rr >> 1) & 3);
      bfv[ni] = *(const bf16x8*)&Bs[cur][rr * 32 + ph * 8];
    }
    #pragma unroll
    for (int mi = 0; mi < 4; ++mi)
      #pragma unroll
      for (int ni = 0; ni < 4; ++ni)
        acc[mi][ni] = __builtin_amdgcn_mfma_f32_16x16x32_bf16(af[mi], bfv[ni], acc[mi][ni], 0, 0, 0);
    __syncthreads();
  }

  // D layout: col=lane&15, row=(lane>>4)*4+reg
  const float* bp = (XMODE == 2) ? (bias + (i64)z * 128) : bias;
  #pragma unroll
  for (int mi = 0; mi < 4; ++mi) {
    const int rowb = m0 + wr * 64 + mi * 16 + sl * 4;
    #pragma unroll
    for (int ni = 0; ni < 4; ++ni) {
      const int col = n0 + wc * 64 + ni * 16 + cL;
      if (col < Nn) {
        float bc = (BIAS == 1) ? bp[col] : 0.f;
        #pragma unroll
        for (int rg = 0; rg < 4; ++rg) {
          float v = acc[mi][ni][rg];
          if (RS) v *= tanhf(rowScale[(i64)zA * sRS + rowb + rg] + rsAdd[zA]);
          v += bc;
          if (BIAS == 2) v += bias[rowb + rg];
          if (BIAS == 3) v += rowScale[(i64)z * sRS + rowb + rg] * bp[col];
          i64 oidx = (i64)(rowb + rg) * ldO + col;
          if (OUTM == 0)      ((float*)Ob)[(i64)z * sO + oidx] = v;
          else if (OUTM == 1) ((unsigned short*)Ob)[(i64)z * sO + oidx] = f2b(v);
          else if (OUTM == 4) {
            float ov = (col < 28) ? tanhf(v * (1.f / 3.f)) : v * (1.f / 1024.f);
            ((float*)Ob)[(i64)z * sO + oidx] = ov;
          } else {
            ((float*)Ob)[(i64)z * sO + oidx] = v;
            O2b[(i64)z * sO2 + oidx] = f2b(v);
          }
        }
      }
    }
  }
}

// ================= fused emo pass =================
__global__ __launch_bounds__(256)
void emo_pass1(const float* __restrict__ emo, const float* __restrict__ eleW,
               unsigned short* __restrict__ emoB, float* __restrict__ colPart,
               float* __restrict__ dotE) {
  int b = blockIdx.y, lc = blockIdx.x;   // 64 chunks x 16 rows
  int t = threadIdx.x, lane = t & 63, w = t >> 6;
  float4 w4 = ((const float4*)eleW)[t];
  float4 acc = make_float4(0.f, 0.f, 0.f, 0.f);
  __shared__ float dw[16][4];
  const float4* src = (const float4*)emo + ((i64)b * 1024 + lc * 16) * 256;
  ushort4* dst = (ushort4*)emoB + ((i64)b * 1024 + lc * 16) * 256;
  #pragma unroll 4
  for (int lr = 0; lr < 16; ++lr) {
    float4 v = src[lr * 256 + t];
    acc.x += v.x; acc.y += v.y; acc.z += v.z; acc.w += v.w;
    float d = v.x * w4.x + v.y * w4.y + v.z * w4.z + v.w * w4.w;
    #pragma unroll
    for (int o = 32; o; o >>= 1) d += __shfl_xor(d, o);
    if (!lane) dw[lr][w] = d;
    ushort4 o4; o4.x = f2b(v.x); o4.y = f2b(v.y); o4.z = f2b(v.z); o4.w = f2b(v.w);
    dst[lr * 256 + t] = o4;
  }
  __syncthreads();
  if (t < 16) dotE[(i64)b * 1024 + lc * 16 + t] = dw[t][0] + dw[t][1] + dw[t][2] + dw[t][3];
  ((float4*)colPart)[((i64)b * 64 + lc) * 256 + t] = acc;
}

// ================= prep kernels =================
__global__ __launch_bounds__(256)
void transpose_all(const float* __restrict__ w_v_W, const float* __restrict__ agg_a_W,
                   const float* __restrict__ agg_c_W, const float* __restrict__ wq_W,
                   const float* __restrict__ wk_W, const float* __restrict__ wv_W,
                   const float* __restrict__ wr_W,
                   unsigned short* __restrict__ wvT, unsigned short* __restrict__ aaT,
                   unsigned short* __restrict__ acT, unsigned short* __restrict__ wqB,
                   unsigned short* __restrict__ kvrT) {
  int bx = blockIdx.x;
  int t = threadIdx.x;
  if (bx >= 84) {   // wqB: fp32->bf16 convert of wq_W [1024x448]
    i64 li = (((i64)(bx - 84) * 32 + blockIdx.y) * 256 + t) * 4;
    float4 v = *(const float4*)(wq_W + li);
    ushort4 o; o.x = f2b(v.x); o.y = f2b(v.y); o.z = f2b(v.z); o.w = f2b(v.w);
    *(ushort4*)(wqB + li) = o;
    return;
  }
  __shared__ float T[32][33];
  const float* in; unsigned short* out; int N, Npad, s0;
  if (bx < 32)      { in = w_v_W;   out = wvT;                     N = 1024; Npad = 1024; s0 = 0; }
  else if (bx < 36) { in = agg_a_W; out = aaT;                     N = 128;  Npad = 128;  s0 = 32; }
  else if (bx < 68) { in = agg_c_W; out = acT;                     N = 1024; Npad = 1024; s0 = 36; }
  else if (bx < 82) { in = wk_W;    out = kvrT;                    N = 448;  Npad = 448;  s0 = 68; }
  else if (bx < 83) { in = wv_W;    out = kvrT + (i64)448 * 1024;  N = 28;   Npad = 28;   s0 = 82; }
  else              { in = wr_W;    out = kvrT + (i64)476 * 1024;  N = 3;    Npad = 36;   s0 = 83; }
  int n0 = (bx - s0) * 32, k0 = blockIdx.y * 32;
  #pragma unroll
  for (int p = 0; p < 4; ++p) {
    int idx = t + 256 * p; int kk = idx >> 5, nn = idx & 31;
    float v = 0.f;
    if (n0 + nn < N) v = in[(i64)(k0 + kk) * N + (n0 + nn)];
    T[nn][kk] = v;
  }
  __syncthreads();
  #pragma unroll
  for (int p = 0; p < 4; ++p) {
    int idx = t + 256 * p; int nn = idx >> 5, kk = idx & 31;
    if (n0 + nn < Npad) out[(i64)(n0 + nn) * 1024 + (k0 + kk)] = f2b(T[nn][kk]);
  }
}

__global__ void kvr_bias_kernel(const float* wkb, const float* wvb, const float* wrb, float* out) {
  int t = blockIdx.x * 256 + threadIdx.x;
  if (t >= 480) return;
  out[t] = (t < 448) ? wkb[t] : (t < 476) ? wvb[t - 448] : (t < 479) ? wrb[t - 476] : 0.f;
}

// fused pool_phr + vconv (grid 16384): pooled bf16 + combine rows 256..511
__global__ void pv_conv(const float* __restrict__ phr, const float* __restrict__ video,
                        unsigned short* __restrict__ pooled, unsigned short* __restrict__ combine) {
  i64 idx = (i64)blockIdx.x * 256 + threadIdx.x;
  if (idx < 2097152) {
    i64 bm = idx >> 8; int c = (int)(idx & 255);
    i64 b = bm >> 8, m = bm & 255;
    const float4* r0 = (const float4*)(phr + (b * 512 + 2 * m) * 1024) + c;
    const float4* r1 = (const float4*)(phr + (b * 512 + 2 * m + 1) * 1024) + c;
    float4 a = *r0, d = *r1;
    ushort4 o;
    o.x = f2b(0.5f * (a.x + d.x)); o.y = f2b(0.5f * (a.y + d.y));
    o.z = f2b(0.5f * (a.z + d.z)); o.w = f2b(0.5f * (a.w + d.w));
    ((ushort4*)pooled)[idx] = o;
  } else {
    i64 j = idx - 2097152;
    i64 b = j >> 16, r = j & 65535;
    float4 v = ((const float4*)video)[j];
    ushort4 o;
    o.x = f2b(v.x); o.y = f2b(v.y); o.z = f2b(v.z); o.w = f2b(v.w);
    ((ushort4*)combine)[b * 131072 + 65536 + r] = o;
  }
}

// combine [b][512][1024] -> combineT [b][1024][512] (bf16, 64x64 LDS tiles)
__global__ __launch_bounds__(256)
void combT_kernel(const unsigned short* __restrict__ in, unsigned short* __restrict__ out) {
  __shared__ unsigned short T[64][68];
  int b = blockIdx.z, mt = blockIdx.y, ft = blockIdx.x;  // grid (16, 8, 32)
  int t = threadIdx.x;
  const unsigned short* src = in + (i64)b * 524288 + (i64)(mt * 64) * 1024 + ft * 64;
  unsigned short* dst = out + (i64)b * 524288 + (i64)(ft * 64) * 512 + mt * 64;
  int r0 = t >> 4, c4 = (t & 15) * 4;
  #pragma unroll
  for (int p = 0; p < 4; ++p) {
    int r = r0 + p * 16;
    ushort4 v = *(const ushort4*)&src[(i64)r * 1024 + c4];
    T[r][c4] = v.x; T[r][c4 + 1] = v.y; T[r][c4 + 2] = v.z; T[r][c4 + 3] = v.w;
  }
  __syncthreads();
  #pragma unroll
  for (int p = 0; p < 4; ++p) {
    int fr = r0 + p * 16;
    ushort4 v;
    v.x = T[c4][fr]; v.y = T[c4 + 1][fr]; v.z = T[c4 + 2][fr]; v.w = T[c4 + 3][fr];
    *(ushort4*)&dst[(i64)fr * 512 + c4] = v;
  }
}

// colsum[b][k] = sum_m attnAT[b][k][m]
__global__ void colsum_kernel(const unsigned short* __restrict__ attnAT, float* __restrict__ colsum) {
  int b = blockIdx.x, k = threadIdx.x;  // 32 blocks x 128
  const ushort4* p = (const ushort4*)(attnAT + ((i64)b * 128 + k) * 512);
  float s = 0.f;
  for (int m4 = 0; m4 < 128; ++m4) {
    ushort4 v = p[m4];
    s += b2f(v.x) + b2f(v.y) + b2f(v.z) + b2f(v.w);
  }
  colsum[b * 128 + k] = s;
}

// fused vt_fill (V rows 0..27, R rows 28..30, pad to 128) and qb. grid (67, 32).
__global__ void vtq_fill(const unsigned short* __restrict__ KVR, const float* __restrict__ wq_b,
                         unsigned short* __restrict__ VT, float* __restrict__ qb) {
  int b = blockIdx.y, bx = blockIdx.x, t = threadIdx.x;
  if (bx < 64) {
    int idx = bx * 256 + t;
    int n = idx >> 7, k = idx & 127;
    unsigned short v = 0;
    if (n < 28)      v = KVR[(i64)b * 61440 + k * 480 + 448 + n];
    else if (n < 31) v = KVR[(i64)b * 61440 + k * 480 + 476 + (n - 28)];
    VT[((i64)b * 128 + n) * 128 + k] = v;
  } else if (t < 128) {
    int ii = bx - 64;
    const int dof_[3] = {0, 256, 384};
    const int kdt_[3] = {256, 128, 64};
    const unsigned short* kp = KVR + (i64)b * 61440 + t * 480 + dof_[ii];
    const float* wb = wq_b + dof_[ii];
    float s = 0.f;
    for (int d = 0; d < kdt_[ii]; ++d) s += b2f(kp[d]) * wb[d];
    qb[(b * 3 + ii) * 128 + t] = s;
  }
}

// ================= softmax =================
__global__ void softmax_attn_a(const float* __restrict__ logits, unsigned short* __restrict__ outT) {
  int gw = (int)(((i64)blockIdx.x * blockDim.x + threadIdx.x) >> 6);
  int lane = threadIdx.x & 63;
  if (gw >= 32 * 512) return;
  int b = gw >> 9, m = gw & 511;
  const float* p = logits + (i64)gw * 128;
  float x0 = p[lane], x1 = p[lane + 64];
  float mx = fmaxf(x0, x1);
  #pragma unroll
  for (int o = 32; o; o >>= 1) mx = fmaxf(mx, __shfl_xor(mx, o));
  float e0 = expf(x0 - mx), e1 = expf(x1 - mx);
  float s = e0 + e1;
  #pragma unroll
  for (int o = 32; o; o >>= 1) s += __shfl_xor(s, o);
  float inv = 1.f / s;
  unsigned short* o0 = outT + (i64)b * 128 * 512 + m;
  o0[(i64)lane * 512] = f2b(e0 * inv);
  o0[(i64)(lane + 64) * 512] = f2b(e1 * inv);
}

// in-place: each warp owns one row of PL
__global__ void softmax_P_bf(const unsigned short* __restrict__ PL, unsigned short* __restrict__ P) {
  i64 gw = ((i64)blockIdx.x * blockDim.x + threadIdx.x) >> 6;
  int lane = threadIdx.x & 63;
  if (gw >= 98304) return;
  const unsigned short* p = PL + gw * 128;
  float x0 = b2f(p[lane]) * TEMP_ISQ, x1 = b2f(p[lane + 64]) * TEMP_ISQ;
  float mx = fmaxf(x0, x1);
  #pragma unroll
  for (int o = 32; o; o >>= 1) mx = fmaxf(mx, __shfl_xor(mx, o));
  float e0 = expf(x0 - mx), e1 = expf(x1 - mx);
  float s = e0 + e1;
  #pragma unroll
  for (int o = 32; o; o >>= 1) s += __shfl_xor(s, o);
  float inv = 1.f / s;
  P[gw * 128 + lane] = f2b(e0 * inv);
  P[gw * 128 + lane + 64] = f2b(e1 * inv);
}

// ================= routing (fused) =================
__global__ __launch_bounds__(256)
void colmean_apool(const float* __restrict__ colPart, const float* __restrict__ aggF,
                   float* __restrict__ Apool) {
  int b = blockIdx.x, t = threadIdx.x, lane = t & 63, w = t >> 6;
  __shared__ float em[1024];
  float4 s = make_float4(0.f, 0.f, 0.f, 0.f);
  const float4* cp = (const float4*)colPart + (i64)b * 64 * 256 + t;
  for (int lc = 0; lc < 64; ++lc) {
    float4 v = cp[lc * 256];
    s.x += v.x; s.y += v.y; s.z += v.z; s.w += v.w;
  }
  em[t * 4 + 0] = s.x * (1.f / 1024.f); em[t * 4 + 1] = s.y * (1.f / 1024.f);
  em[t * 4 + 2] = s.z * (1.f / 1024.f); em[t * 4 + 3] = s.w * (1.f / 1024.f);
  __syncthreads();
  for (int k = w; k < 128; k += 4) {
    const float* ag = aggF + ((i64)b * 128 + k) * 1024;
    float d = 0.f;
    #pragma unroll
    for (int j = 0; j < 16; ++j) { int e = j * 64 + lane; d += em[e] * ag[e]; }
    #pragma unroll
    for (int o = 32; o; o >>= 1) d += __shfl_down(d, o);
    if (!lane) Apool[b * 128 + k] = d;
  }
}

__global__ __launch_bounds__(256)
void route_rb(const float* __restrict__ Apool, const float* __restrict__ aggF,
              const float* __restrict__ eleW, const float* __restrict__ eleb,
              float* __restrict__ rbv) {
  int b = blockIdx.x, t = threadIdx.x;
  __shared__ float Ap[128];
  if (t < 128) Ap[t] = Apool[b * 128 + t];
  __syncthreads();
  float4 r = make_float4(0.f, 0.f, 0.f, 0.f);
  const float4* ag = (const float4*)(aggF + (i64)b * 128 * 1024) + t;
  #pragma unroll 8
  for (int k = 0; k < 128; ++k) {
    float a = Ap[k];
    float4 v = ag[(i64)k * 256];
    r.x += a * v.x; r.y += a * v.y; r.z += a * v.z; r.w += a * v.w;
  }
  float4 w4 = ((const float4*)(eleW + 1024))[t];
  float d = r.x * w4.x + r.y * w4.y + r.z * w4.z + r.w * w4.w;
  __shared__ float red[256];
  red[t] = d; __syncthreads();
  for (int o = 128; o > 0; o >>= 1) { if (t < o) red[t] += red[t + o]; __syncthreads(); }
  if (t == 0) rbv[b] = red[0] + eleb[0];
}

// ================= gate / final =================
__global__ void gate_kernel(const float* __restrict__ O, float* __restrict__ gate) {
  int b = blockIdx.x, t = threadIdx.x;  // 128 threads
  __shared__ float red[128];
  __shared__ float rd[3];
  for (int i = 0; i < 3; ++i) {
    const float* op = O + ((i64)(b * 3 + i) * 1024) * 32 + 28 + i;
    float s = 0.f;
    #pragma unroll
    for (int l = t; l < 1024; l += 128) s += op[(i64)l * 32];
    red[t] = s; __syncthreads();
    for (int o = 64; o > 0; o >>= 1) { if (t < o) red[t] += red[t + o]; __syncthreads(); }
    if (t == 0) rd[i] = red[0];
    __syncthreads();
  }
  if (t == 0) {
    float m = fmaxf(rd[0], fmaxf(rd[1], rd[2]));
    float e0 = expf(rd[0] - m), e1 = expf(rd[1] - m), e2 = expf(rd[2] - m);
    float inv = 1.f / (e0 + e1 + e2);
    gate[b * 3 + 0] = e0 * inv; gate[b * 3 + 1] = e1 * inv; gate[b * 3 + 2] = e2 * inv;
  }
}

__global__ __launch_bounds__(256)
void final_kernel(const unsigned short* __restrict__ emoB, const float* __restrict__ dotE,
                  const float* __restrict__ rbv, const float* __restrict__ O,
                  const float* __restrict__ gate, float* __restrict__ out) {
  i64 bl = blockIdx.x;
  int b = (int)(bl >> 10), l = (int)(bl & 1023);
  __shared__ float Gg[16];
  int t = threadIdx.x;
  if (t < 16) {
    float g0 = gate[b * 3], g1 = gate[b * 3 + 1], g2 = gate[b * 3 + 2];
    float o0 = O[((i64)(b * 3 + 0) * 1024 + l) * 32 + (t >> 2)];
    float o1 = O[((i64)(b * 3 + 1) * 1024 + l) * 32 + 4 + (t >> 1)];
    float o2 = O[((i64)(b * 3 + 2) * 1024 + l) * 32 + 12 + t];
    Gg[t] = g0 * o0 + g1 * o1 + g2 * o2;
  }
  __syncthreads();
  float re = tanhf(dotE[bl] + rbv[b]);
  ushort4 e4 = ((const ushort4*)(emoB + bl * 1024))[t];
  float g = 1.f + re * Gg[t >> 4];
  ((float4*)(out + bl * 1024))[t] =
      make_float4(b2f(e4.x) * g, b2f(e4.y) * g, b2f(e4.z) * g, b2f(e4.w) * g);
}

// ================= launcher =================
extern "C" void kernel_launch(void* const* d_in, const int* in_sizes, int n_in,
                              void* d_out, int out_size, void* d_ws, size_t ws_size,
                              hipStream_t stream) {
  const float* emo     = (const float*)d_in[0];
  const float* phr     = (const float*)d_in[1];
  const float* video   = (const float*)d_in[2];
  const float* w_v_W   = (const float*)d_in[3];
  const float* w_v_b   = (const float*)d_in[4];
  const float* agg_a_W = (const float*)d_in[5];
  const float* agg_a_b = (const float*)d_in[6];
  const float* agg_c_W = (const float*)d_in[7];
  const float* agg_c_b = (const float*)d_in[8];
  const float* ele_W   = (const float*)d_in[9];
  const float* ele_b   = (const float*)d_in[10];
  const float* wq_W    = (const float*)d_in[11];
  const float* wq_b    = (const float*)d_in[12];
  const float* wk_W    = (const float*)d_in[13];
  const float* wk_b    = (const float*)d_in[14];
  const float* wv_W    = (const float*)d_in[15];
  const float* wv_b    = (const float*)d_in[16];
  const float* wr_W    = (const float*)d_in[17];
  const float* wr_b    = (const float*)d_in[18];

  char* ws = (char*)d_ws;
  // ---- region map (bytes) ----
  const i64 oEmoB    = 0;            // ushort [32,1024,1024] 67,108,864 (live to end)
  const i64 oCombine = 67108864;     // ushort [32,512,1024] (dead after combT)
  const i64 oS1B     = 67108864;     //   overlay: ushort [32,128,1024] 8,388,608 (S1 out, dead after S2)
  const i64 oP       = 67108864;     //   overlay: ushort [96,1024,128]; softmax IN-PLACE
  const i64 oPooled  = 100663296;    // ushort [32,256,1024] (dead after G1)
  const i64 oLogitsA = 100663296;    //   overlay: float [32,512,128] (dead after softmax_attn_a)
  const i64 oAggF    = 100663296;    //   overlay: float [32,128,1024] (dead after route_rb)
  const i64 oO       = 100663296;    //   overlay: float [96,1024,32] (written by OV)
  const i64 oCT      = 117440512;    // combineT ushort [32,1024,512] (dead after S1)
  const i64 oW2T     = 117440512;    //   overlay: ushort [96,128,1024]
  const i64 oAttnAT  = 150994944;    // ushort [32,128,512] 4,194,304
  const i64 oAggB    = 155189248;    // ushort [32,128,1024] 8,388,608
  const i64 oWvT     = 163577856;    // 2,097,152
  const i64 oAaT     = 165675008;    // 262,144
  const i64 oAcT     = 165937152;    // 2,097,152
  const i64 oWqB     = 168034304;    // ushort [1024,448]
  const i64 oKvrT    = 169082880;    // 1,048,576
  const i64 oKVR     = 170131456;    // ushort [32,128,480] 3,932,160
  const i64 oVT      = 174063616;    // ushort [32,128,128] 1,048,576
  const i64 oKvrB    = 175112192;    // 4,096
  const i64 oColPart = 175247360;    // float [32,64,1024] 8,388,608
  const i64 oDotE    = 183635968;    // 131,072
  const i64 oApool   = 183767040;    // 16,384
  const i64 oQb      = 183783424;    // float [96,128] 49,152
  const i64 oRb      = 183914496;    // 256
  const i64 oGate    = 184307968;    // 512
  const i64 oColsum  = 184308480;    // float [32,128] 16,384

  unsigned short* emoB    = (unsigned short*)(ws + oEmoB);
  unsigned short* combine = (unsigned short*)(ws + oCombine);
  unsigned short* S1B     = (unsigned short*)(ws + oS1B);
  unsigned short* P       = (unsigned short*)(ws + oP);
  unsigned short* pooled  = (unsigned short*)(ws + oPooled);
  float*          logitsA = (float*)(ws + oLogitsA);
  float*          aggF    = (float*)(ws + oAggF);
  float*          O       = (float*)(ws + oO);
  unsigned short* combineT= (unsigned short*)(ws + oCT);
  unsigned short* W2T     = (unsigned short*)(ws + oW2T);
  unsigned short* attnAT  = (unsigned short*)(ws + oAttnAT);
  unsigned short* aggB    = (unsigned short*)(ws + oAggB);
  unsigned short* wvT     = (unsigned short*)(ws + oWvT);
  unsigned short* aaT     = (unsigned short*)(ws + oAaT);
  unsigned short* acT     = (unsigned short*)(ws + oAcT);
  unsigned short* wqB     = (unsigned short*)(ws + oWqB);
  unsigned short* kvrT    = (unsigned short*)(ws + oKvrT);
  unsigned short* KVR     = (unsigned short*)(ws + oKVR);
  unsigned short* VT      = (unsigned short*)(ws + oVT);
  float*          kvrB    = (float*)(ws + oKvrB);
  float*          colPart = (float*)(ws + oColPart);
  float*          dotE    = (float*)(ws + oDotE);
  float*          Apool   = (float*)(ws + oApool);
  float*          qb      = (float*)(ws + oQb);
  float*          rbv     = (float*)(ws + oRb);
  float*          gate    = (float*)(ws + oGate);
  float*          colsum  = (float*)(ws + oColsum);

  dim3 blk(256);

  // fused emo pass: colPart + dotE + emoB
  emo_pass1<<<dim3(64, 32), blk, 0, stream>>>(emo, ele_W, emoB, colPart, dotE);

  // weight prep (single launch) + bias pack
  transpose_all<<<dim3(98, 32), blk, 0, stream>>>(w_v_W, agg_a_W, agg_c_W, wq_W, wk_W, wv_W, wr_W,
                                                  wvT, aaT, acT, wqB, kvrT);
  kvr_bias_kernel<<<2, blk, 0, stream>>>(wk_b, wv_b, wr_b, kvrB);

  // feature aggregation
  pv_conv<<<16384, blk, 0, stream>>>(phr, video, pooled, combine);
  // G1: combine rows 0..255 = pooled @ w_v + b
  gemm_mfma<1, 1, 0, 1><<<dim3(8, 2, 32), blk, 0, stream>>>(pooled, 262144, wvT, 0, w_v_b,
      (void*)combine, 524288, nullptr, 0, 1024, 1024, 1024, 1024, 1024, nullptr, 0, nullptr);
  // G2: attn logits
  gemm_mfma<1, 0, 0, 1><<<dim3(1, 4, 32), blk, 0, stream>>>(combine, 524288, aaT, 0, agg_a_b,
      (void*)logitsA, 65536, nullptr, 0, 128, 1024, 1024, 1024, 128, nullptr, 0, nullptr);
  softmax_attn_a<<<4096, blk, 0, stream>>>(logitsA, attnAT);
  colsum_kernel<<<32, 128, 0, stream>>>(attnAT, colsum);
  // transpose combine -> combineT (m-contiguous rows for S1's B-operand)
  combT_kernel<<<dim3(16, 8, 32), blk, 0, stream>>>(combine, combineT);

  // S1 = attnAT @ combineT^T : [32][128 k][1024 f] bf16  (reassociated aggregation)
  gemm_mfma<0, 1, 0, 1><<<dim3(8, 1, 32), blk, 0, stream>>>(attnAT, 65536, combineT, 524288, nullptr,
      (void*)S1B, 131072, nullptr, 0, 1024, 512, 512, 512, 1024, nullptr, 0, nullptr);
  // S2 = S1 @ agg_c + colsum[k]*agg_c_b[e]  -> aggF (fp32) + aggB (bf16)
  gemm_mfma<3, 2, 0, 1><<<dim3(8, 1, 32), blk, 0, stream>>>(S1B, 131072, acT, 0, agg_c_b,
      (void*)aggF, 131072, aggB, 131072, 1024, 1024, 1024, 1024, 1024, colsum, 128, nullptr);

  // element routing (fp32, fused)
  colmean_apool<<<32, blk, 0, stream>>>(colPart, aggF, Apool);
  route_rb<<<32, blk, 0, stream>>>(Apool, aggF, ele_W, ele_b, rbv);

  // KVR = agg @ [wk|wv|wr] + bias
  gemm_mfma<1, 1, 0, 1><<<dim3(4, 1, 32), blk, 0, stream>>>(aggB, 131072, kvrT, 0, kvrB,
      (void*)KVR, 61440, nullptr, 0, 480, 1024, 1024, 1024, 480, nullptr, 0, nullptr);
  vtq_fill<<<dim3(67, 32), blk, 0, stream>>>(KVR, wq_b, VT, qb);

  // W2T[z=(b,i)] = K_i[b] @ wq_i^T  (bf16)
  gemm_mfma<0, 1, 0, 1, 3><<<dim3(8, 1, 96), blk, 0, stream>>>(KVR, 61440, wqB, 0, nullptr,
      (void*)W2T, 131072, nullptr, 0, 1024, 0, 480, 448, 1024, nullptr, 0, nullptr);

  // PL = tanh(dotE+rb) * (emoB @ W2T^T) + qb  (bf16 logits)
  gemm_mfma<1, 1, 1, 1, 2><<<dim3(1, 8, 96), blk, 0, stream>>>(emoB, 1048576, W2T, 131072, qb,
      (void*)P, 131072, nullptr, 0, 128, 1024, 1024, 1024, 128, dotE, 1024, rbv);

  softmax_P_bf<<<24576, blk, 0, stream>>>(P, P);

  // OV: O[:, :28] = tanh((P @ VT^T)/3); O[:, 28..30] = (P @ R)/1024
  gemm_mfma<0, 4, 0, 3><<<dim3(1, 8, 96), blk, 0, stream>>>(P, 131072, VT, 16384, nullptr,
      (void*)O, 32768, nullptr, 0, 31, 128, 128, 128, 32, nullptr, 0, nullptr);

  gate_kernel<<<32, 128, 0, stream>>>(O, gate);
  final_kernel<<<32768, blk, 0, stream>>>(emoB, dotE, rbv, O, gate, (float*)d_out);
}